// Round 8
// baseline (1081.276 us; speedup 1.0000x reference)
//
#include <hip/hip_runtime.h>
#include <hip/hip_bf16.h>
#include <math.h>

#define IN_DIM 128
#define LAT 32
#define HID 128
#define RSHIFT 8          // nodes per bucket = 256
#define RANGE 256
#define KMAX 1024
#define PART_CH 16384
#define GIN_ROWS 32       // rows per block in gemm_in

typedef unsigned short u16;

__device__ __forceinline__ float bf2f(u16 v) {
    return __uint_as_float(((unsigned int)v) << 16);
}
__device__ __forceinline__ u16 f2bf(float f) {
    unsigned int u = __float_as_uint(f);
    u += 0x7fff + ((u >> 16) & 1);   // round-to-nearest-even
    return (u16)(u >> 16);
}
__device__ __forceinline__ float bflo(unsigned int w) {
    return __uint_as_float(w << 16);
}
__device__ __forceinline__ float bfhi(unsigned int w) {
    return __uint_as_float(w & 0xffff0000u);
}

// ---------------- setup ----------------

__global__ void pmap_kernel(const int* __restrict__ batch, int* __restrict__ pmap, int N) {
    int v = blockIdx.x * blockDim.x + threadIdx.x;
    if (v >= N) return;
    int b = batch[v];
    int prev = (v == 0) ? -1 : batch[v - 1];
    pmap[v] = (b != prev) ? (b + 1) : 0;
}

__global__ void compute_idx_kernel(const int* __restrict__ batch, int* __restrict__ idx,
                                   int N, int G) {
    int g = blockIdx.x * blockDim.x + threadIdx.x;
    if (g >= G) return;
    int lo = 0, hi = N;
    while (lo < hi) {
        int mid = (lo + hi) >> 1;
        if (batch[mid] < g) lo = mid + 1; else hi = mid;
    }
    idx[g] = lo;
}

// ---------------- radix-partition CSR build ----------------

__global__ void bucket_hist_kernel(const int* __restrict__ ei, int* __restrict__ bucketTot,
                                   long long E, int K) {
    __shared__ int hist[KMAX];
    for (int b = threadIdx.x; b < K; b += blockDim.x) hist[b] = 0;
    __syncthreads();
    long long tid = (long long)blockIdx.x * blockDim.x + threadIdx.x;
    long long stride = (long long)gridDim.x * blockDim.x;
    for (long long e = tid; e < E; e += stride) {
        int d = ei[E + e];
        atomicAdd(&hist[d >> RSHIFT], 1);
    }
    __syncthreads();
    for (int b = threadIdx.x; b < K; b += blockDim.x) {
        int h = hist[b];
        if (h) atomicAdd(&bucketTot[b], h);
    }
}

__global__ void bucket_scan_kernel(const int* __restrict__ bucketTot, int* __restrict__ bucketStart,
                                   int* __restrict__ bucketCursor, int K, int Etot,
                                   int* __restrict__ rowptr, int N) {
    __shared__ int s[KMAX];
    int t = threadIdx.x;
    int v = (t < K) ? bucketTot[t] : 0;
    s[t] = v;
    __syncthreads();
    for (int off = 1; off < KMAX; off <<= 1) {
        int tmp = (t >= off) ? s[t - off] : 0;
        __syncthreads();
        s[t] += tmp;
        __syncthreads();
    }
    if (t < K) {
        int excl = s[t] - v;
        bucketStart[t] = excl;
        bucketCursor[t] = excl;
    }
    if (t == 0) {
        bucketStart[K] = Etot;
        rowptr[N] = Etot;
    }
}

__global__ void partition_kernel(const int* __restrict__ ei, int* __restrict__ bucketCursor,
                                 unsigned int* __restrict__ pairs, long long E, int K) {
    __shared__ int hist[KMAX];
    __shared__ int off[KMAX];
    __shared__ int cur[KMAX];
    int t = threadIdx.x;
    for (int b = t; b < K; b += blockDim.x) { hist[b] = 0; cur[b] = 0; }
    __syncthreads();
    long long e0 = (long long)blockIdx.x * PART_CH;
    int cnt = (int)min((long long)PART_CH, E - e0);
    for (int i = t; i < cnt; i += blockDim.x) {
        int d = ei[E + e0 + i];
        atomicAdd(&hist[d >> RSHIFT], 1);
    }
    __syncthreads();
    for (int b = t; b < K; b += blockDim.x) {
        int h = hist[b];
        off[b] = h ? atomicAdd(&bucketCursor[b], h) : 0;
    }
    __syncthreads();
    for (int i = t; i < cnt; i += blockDim.x) {
        long long e = e0 + i;
        unsigned int s = (unsigned int)ei[e];
        int d = ei[E + e];
        int b = d >> RSHIFT;
        int p = off[b] + atomicAdd(&cur[b], 1);
        pairs[p] = (s << RSHIFT) | (unsigned int)(d & (RANGE - 1));
    }
}

__global__ void build_csr_kernel(const unsigned int* __restrict__ pairs,
                                 const int* __restrict__ bucketStart,
                                 int* __restrict__ rowptr, float* __restrict__ dinv,
                                 int* __restrict__ csr_src, int N) {
    __shared__ int hist[RANGE];
    __shared__ int scanb[RANGE];
    __shared__ int cursor[RANGE];
    int b = blockIdx.x;
    int t = threadIdx.x;
    int base = b << RSHIFT;
    int s0 = bucketStart[b];
    int s1 = bucketStart[b + 1];
    int cnt = s1 - s0;
    hist[t] = 0;
    __syncthreads();
    for (int i = t; i < cnt; i += RANGE) {
        unsigned int p = pairs[s0 + i];
        atomicAdd(&hist[p & (RANGE - 1)], 1);
    }
    __syncthreads();
    int deg = hist[t];
    scanb[t] = deg;
    __syncthreads();
    for (int off = 1; off < RANGE; off <<= 1) {
        int tmp = (t >= off) ? scanb[t - off] : 0;
        __syncthreads();
        scanb[t] += tmp;
        __syncthreads();
    }
    int excl = scanb[t] - deg;
    int node = base + t;
    if (node < N) {
        rowptr[node] = s0 + excl;
        dinv[node] = rsqrtf((float)(deg + 1));   // +1 self-loop
    }
    cursor[t] = s0 + excl;
    __syncthreads();
    for (int i = t; i < cnt; i += RANGE) {
        unsigned int p = pairs[s0 + i];
        int slot = atomicAdd(&cursor[p & (RANGE - 1)], 1);
        csr_src[slot] = (int)(p >> RSHIFT);
    }
}

// ---------------- input transform: tp1 = (x@W1)*dinv, bf16 ----------------

__global__ void gemm_in_kernel(const float* __restrict__ x, const float* __restrict__ W,
                               const float* __restrict__ dinv, u16* __restrict__ tp, int N) {
    __shared__ float Wl[IN_DIM * LAT];         // 16 KB
    __shared__ float Xl[GIN_ROWS * IN_DIM];    // 16 KB
    int t = threadIdx.x;
    for (int i = t; i < IN_DIM * LAT; i += 256) Wl[i] = W[i];
    long long rowBase = (long long)blockIdx.x * GIN_ROWS;
    int nrow = min(GIN_ROWS, (int)(N - rowBase));
    {
        const float4* x4 = reinterpret_cast<const float4*>(x + rowBase * IN_DIM);
        float4* X4 = reinterpret_cast<float4*>(Xl);
        int nf4 = nrow * (IN_DIM / 4);
        for (int i = t; i < nf4; i += 256) X4[i] = x4[i];   // coalesced
    }
    __syncthreads();
    int g = t >> 5;            // col-group 0..7
    int c = t & 31;
    int r0 = g * 4;            // 4 local rows per group
    float acc0 = 0.f, acc1 = 0.f, acc2 = 0.f, acc3 = 0.f;
#pragma unroll 4
    for (int k = 0; k < IN_DIM; k += 4) {
        float w0 = Wl[(k + 0) * LAT + c];
        float w1 = Wl[(k + 1) * LAT + c];
        float w2 = Wl[(k + 2) * LAT + c];
        float w3 = Wl[(k + 3) * LAT + c];
        float4 xa = *reinterpret_cast<const float4*>(&Xl[(r0 + 0) * IN_DIM + k]);
        float4 xb = *reinterpret_cast<const float4*>(&Xl[(r0 + 1) * IN_DIM + k]);
        float4 xc = *reinterpret_cast<const float4*>(&Xl[(r0 + 2) * IN_DIM + k]);
        float4 xd = *reinterpret_cast<const float4*>(&Xl[(r0 + 3) * IN_DIM + k]);
        acc0 += xa.x * w0 + xa.y * w1 + xa.z * w2 + xa.w * w3;
        acc1 += xb.x * w0 + xb.y * w1 + xb.z * w2 + xb.w * w3;
        acc2 += xc.x * w0 + xc.y * w1 + xc.z * w2 + xc.w * w3;
        acc3 += xd.x * w0 + xd.y * w1 + xd.z * w2 + xd.w * w3;
    }
    long long rr = rowBase + r0;
    if (r0 + 0 < nrow) tp[(rr + 0) * LAT + c] = f2bf(acc0 * dinv[rr + 0]);
    if (r0 + 1 < nrow) tp[(rr + 1) * LAT + c] = f2bf(acc1 * dinv[rr + 1]);
    if (r0 + 2 < nrow) tp[(rr + 2) * LAT + c] = f2bf(acc2 * dinv[rr + 2]);
    if (r0 + 3 < nrow) tp[(rr + 3) * LAT + c] = f2bf(acc3 * dinv[rr + 3]);
}

// ---------------- feature-quarter gather + tanh ----------------
// Pass q gathers feats [8q,8q+8) from an N x 8 slice (3.2 MB, L2-resident per XCD).
// Wave = 2 nodes (32 edge-lanes each); lane = 1 edge, 16B quarter-row load.
// csr_src loaded nontemporally so the stream doesn't evict the resident table.

__global__ void gather_q_kernel(const int* __restrict__ rowptr, const int* __restrict__ csr_src,
                                const u16* __restrict__ tp, const float* __restrict__ dinv,
                                const float* __restrict__ bcur, const int* __restrict__ pmap,
                                float* __restrict__ pooled, int colOff, int q,
                                u16* __restrict__ hq, const int* __restrict__ vmap,
                                int Nv) {
    int wv = threadIdx.x >> 6;
    int lane = threadIdx.x & 63;
    int slot = lane & 31;
    int vi = (blockIdx.x * 4 + wv) * 2 + (lane >> 5);
    bool vok = vi < Nv;
    int v = 0;
    if (vok) v = vmap ? vmap[vi] : vi;
    int start = 0, end = 0;
    if (vok) { start = rowptr[v]; end = rowptr[v + 1]; }
    int deg = end - start;
    int iters = (deg + 31) >> 5;
    int itA = __shfl(iters, 0, 64);
    int itB = __shfl(iters, 32, 64);
    int itW = itA > itB ? itA : itB;

    float c0 = 0.f, c1 = 0.f, c2 = 0.f, c3 = 0.f,
          c4 = 0.f, c5 = 0.f, c6 = 0.f, c7 = 0.f;
    const u16* tq = tp + (q << 3);
    for (int k = 0; k < itW; ++k) {
        int e = start + slot + (k << 5);
        if (e < end) {
            int sj = __builtin_nontemporal_load(csr_src + e);
            const uint4 w = *reinterpret_cast<const uint4*>(tq + ((size_t)sj << 5));
            c0 += bflo(w.x); c1 += bfhi(w.x);
            c2 += bflo(w.y); c3 += bfhi(w.y);
            c4 += bflo(w.z); c5 += bfhi(w.z);
            c6 += bflo(w.w); c7 += bfhi(w.w);
        }
    }
    if (slot == 0 && vok) {   // self-loop term
        const uint4 w = *reinterpret_cast<const uint4*>(tq + ((size_t)v << 5));
        c0 += bflo(w.x); c1 += bfhi(w.x);
        c2 += bflo(w.y); c3 += bfhi(w.y);
        c4 += bflo(w.z); c5 += bfhi(w.z);
        c6 += bflo(w.w); c7 += bfhi(w.w);
    }
#pragma unroll
    for (int d = 1; d <= 16; d <<= 1) {   // allreduce within each 32-half
        c0 += __shfl_xor(c0, d, 64); c1 += __shfl_xor(c1, d, 64);
        c2 += __shfl_xor(c2, d, 64); c3 += __shfl_xor(c3, d, 64);
        c4 += __shfl_xor(c4, d, 64); c5 += __shfl_xor(c5, d, 64);
        c6 += __shfl_xor(c6, d, 64); c7 += __shfl_xor(c7, d, 64);
    }
    if (!vok) return;
    int j = slot & 7;
    float sv = (j < 4) ? ((j < 2) ? (j == 0 ? c0 : c1) : (j == 2 ? c2 : c3))
                       : ((j < 6) ? (j == 4 ? c4 : c5) : (j == 6 ? c6 : c7));
    float dv = dinv[v];
    float hv = tanhf(dv * sv + bcur[(q << 3) + j]);
    if (slot < 8) {
        if (hq) hq[((size_t)v << 5) + (q << 3) + j] = f2bf(hv);
        int pg = pmap[v];
        if (pg) pooled[(size_t)(pg - 1) * (3 * LAT) + colOff + (q << 3) + j] = hv;
    }
}

// ---------------- latent GEMM: tp = (h @ W) * dinv, bf16 in/out ----------------

__global__ void gemm_lat_kernel(const u16* __restrict__ h, const float* __restrict__ W,
                                const float* __restrict__ dinv, u16* __restrict__ tp, int N) {
    __shared__ float Wl[LAT * LAT];
    for (int i = threadIdx.x; i < LAT * LAT; i += 256) Wl[i] = W[i];
    __syncthreads();
    int gid = blockIdx.x * 256 + threadIdx.x;
    if (gid >= N * LAT) return;
    int v = gid >> 5, c = gid & 31;
    const uint4* hr = reinterpret_cast<const uint4*>(h + ((size_t)v << 5));
    uint4 a0 = hr[0], a1 = hr[1], a2 = hr[2], a3 = hr[3];   // same addr per 32 lanes: broadcast
    float acc = 0.f;
    int kk = 0;
#define GL_ACC(wrd) { acc += bflo(wrd) * Wl[kk * LAT + c]; acc += bfhi(wrd) * Wl[(kk + 1) * LAT + c]; kk += 2; }
    GL_ACC(a0.x) GL_ACC(a0.y) GL_ACC(a0.z) GL_ACC(a0.w)
    GL_ACC(a1.x) GL_ACC(a1.y) GL_ACC(a1.z) GL_ACC(a1.w)
    GL_ACC(a2.x) GL_ACC(a2.y) GL_ACC(a2.z) GL_ACC(a2.w)
    GL_ACC(a3.x) GL_ACC(a3.y) GL_ACC(a3.z) GL_ACC(a3.w)
#undef GL_ACC
    tp[gid] = f2bf(acc * dinv[v]);
}

// ---------------- MLP head ----------------

__global__ void mlp_head_kernel(const float* __restrict__ pooled,
                                const float* __restrict__ Wl1, const float* __restrict__ bl1,
                                const float* __restrict__ Wl2, const float* __restrict__ bl2,
                                float* __restrict__ out, int G) {
    __shared__ float prow[3 * LAT];
    __shared__ float red0[HID];
    __shared__ float red1[HID];
    int g = blockIdx.x;
    int j = threadIdx.x;
    if (j < 3 * LAT) prow[j] = pooled[(long long)g * (3 * LAT) + j];
    __syncthreads();
    float acc = bl1[j];
#pragma unroll 8
    for (int k = 0; k < 3 * LAT; k++) acc += prow[k] * Wl1[k * HID + j];
    float hj = fmaxf(acc, 0.f);
    red0[j] = hj * Wl2[j * 2 + 0];
    red1[j] = hj * Wl2[j * 2 + 1];
    __syncthreads();
    for (int s = HID / 2; s > 0; s >>= 1) {
        if (j < s) { red0[j] += red0[j + s]; red1[j] += red1[j + s]; }
        __syncthreads();
    }
    if (j == 0) {
        float l0 = red0[0] + bl2[0];
        float l1 = red1[0] + bl2[1];
        float m = fmaxf(l0, l1);
        float lse = m + logf(expf(l0 - m) + expf(l1 - m));
        out[(long long)g * 2 + 0] = l0 - lse;
        out[(long long)g * 2 + 1] = l1 - lse;
    }
}

// ---------------- launch ----------------

extern "C" void kernel_launch(void* const* d_in, const int* in_sizes, int n_in,
                              void* d_out, int out_size, void* d_ws, size_t ws_size,
                              hipStream_t stream) {
    const float* x    = (const float*)d_in[0];
    const int*   ei   = (const int*)d_in[1];
    const int*   batch= (const int*)d_in[2];
    const float* W1   = (const float*)d_in[3];
    const float* b1   = (const float*)d_in[4];
    const float* W2   = (const float*)d_in[5];
    const float* b2   = (const float*)d_in[6];
    const float* W3   = (const float*)d_in[7];
    const float* b3   = (const float*)d_in[8];
    const float* Wl1  = (const float*)d_in[9];
    const float* bl1  = (const float*)d_in[10];
    const float* Wl2  = (const float*)d_in[11];
    const float* bl2  = (const float*)d_in[12];
    float* out = (float*)d_out;

    const int N = in_sizes[2];
    const long long E = (long long)in_sizes[1] / 2;
    const int G = out_size / 2;
    const int K = (N + RANGE - 1) >> RSHIFT;

    // workspace layout
    char* ws = (char*)d_ws;
    size_t off = 0;
    char*  regionA = ws + off;           off += (size_t)E * 4;   // pairs; later tpA(12.8M)+hbuf(12.8M)
    char*  bufB    = ws + off;           off += (size_t)N * LAT * 2;
    int*   csr_src = (int*)  (ws + off); off += (size_t)E * 4;
    float* dinv    = (float*)(ws + off); off += (size_t)N * 4;
    int*   rowptr  = (int*)  (ws + off); off += (size_t)(N + 1) * 4;
    int*   pmap    = (int*)  (ws + off); off += (size_t)N * 4;
    int*   idx     = (int*)  (ws + off); off += (size_t)G * 4;
    float* pooled  = (float*)(ws + off); off += (size_t)G * (3 * LAT) * 4;
    int*   bucketTot    = (int*)(ws + off); off += (KMAX + 1) * 4;
    int*   bucketStart  = (int*)(ws + off); off += (KMAX + 1) * 4;
    int*   bucketCursor = (int*)(ws + off); off += KMAX * 4;

    unsigned int* pairs = (unsigned int*)regionA;        // dead before gemm_in writes tpA
    u16* tpA  = (u16*)regionA;                            // N*32 bf16 = 12.8 MB
    u16* hbuf = (u16*)(regionA + (size_t)N * LAT * 2);    // N*32 bf16 = 12.8 MB (fits: E*4 == 2*N*32*2)
    u16* tpB  = (u16*)bufB;

    const int BS = 256;
    const int gqBlocks  = (N + 7) / 8;                   // wave = 2 nodes, 4 waves/block
    const int gq3Blocks = (G + 7) / 8;
    const int nvBlocks  = (N * LAT + BS - 1) / BS;
    const int ginBlocks = (N + GIN_ROWS - 1) / GIN_ROWS;
    const int partBlocks = (int)((E + PART_CH - 1) / PART_CH);

    // ---- CSR build via radix partition ----
    hipMemsetAsync(bucketTot, 0, (size_t)(KMAX + 1) * 4, stream);
    pmap_kernel<<<(N + BS - 1) / BS, BS, 0, stream>>>(batch, pmap, N);
    compute_idx_kernel<<<(G + BS - 1) / BS, BS, 0, stream>>>(batch, idx, N, G);
    bucket_hist_kernel<<<256, BS, 0, stream>>>(ei, bucketTot, E, K);
    bucket_scan_kernel<<<1, KMAX, 0, stream>>>(bucketTot, bucketStart, bucketCursor, K, (int)E, rowptr, N);
    partition_kernel<<<partBlocks, BS, 0, stream>>>(ei, bucketCursor, pairs, E, K);
    build_csr_kernel<<<K, RANGE, 0, stream>>>(pairs, bucketStart, rowptr, dinv, csr_src, N);

    // ---- layer 1 transform ----
    gemm_in_kernel<<<ginBlocks, BS, 0, stream>>>(x, W1, dinv, tpA, N);

    // ---- layer 1: 4 feature-quarter gathers (tpA -> hbuf), then tp2 = (h@W2)*dinv ----
    for (int q = 0; q < 4; q++)
        gather_q_kernel<<<gqBlocks, BS, 0, stream>>>(rowptr, csr_src, tpA, dinv, b1, pmap,
                                                     pooled, 0, q, hbuf, (const int*)nullptr, N);
    gemm_lat_kernel<<<nvBlocks, BS, 0, stream>>>(hbuf, W2, dinv, tpB, N);

    // ---- layer 2: (tpB -> hbuf), then tp3 = (h@W3)*dinv ----
    for (int q = 0; q < 4; q++)
        gather_q_kernel<<<gqBlocks, BS, 0, stream>>>(rowptr, csr_src, tpB, dinv, b2, pmap,
                                                     pooled, LAT, q, hbuf, (const int*)nullptr, N);
    gemm_lat_kernel<<<nvBlocks, BS, 0, stream>>>(hbuf, W3, dinv, tpA, N);

    // ---- layer 3: h3 only needed at the G readout nodes ----
    for (int q = 0; q < 4; q++)
        gather_q_kernel<<<gq3Blocks, BS, 0, stream>>>(rowptr, csr_src, tpA, dinv, b3, pmap,
                                                      pooled, 2 * LAT, q, (u16*)nullptr, idx, G);

    // ---- MLP head ----
    mlp_head_kernel<<<G, HID, 0, stream>>>(pooled, Wl1, bl1, Wl2, bl2, out, G);
}

// Round 9
// 935.760 us; speedup vs baseline: 1.1555x; 1.1555x over previous
//
#include <hip/hip_runtime.h>
#include <hip/hip_bf16.h>
#include <math.h>

#define IN_DIM 128
#define LAT 32
#define HID 128
#define RSHIFT 8          // nodes per bucket = 256
#define RANGE 256
#define KMAX 1024
#define PART_CH 4096      // round-8 fix: 16384 gave 391 blocks -> 14% occupancy
#define GIN_ROWS 32       // rows per block in gemm_in

typedef unsigned short u16;

__device__ __forceinline__ float bf2f(u16 v) {
    return __uint_as_float(((unsigned int)v) << 16);
}
__device__ __forceinline__ u16 f2bf(float f) {
    unsigned int u = __float_as_uint(f);
    u += 0x7fff + ((u >> 16) & 1);   // round-to-nearest-even
    return (u16)(u >> 16);
}
__device__ __forceinline__ float bflo(unsigned int w) {
    return __uint_as_float(w << 16);
}
__device__ __forceinline__ float bfhi(unsigned int w) {
    return __uint_as_float(w & 0xffff0000u);
}

// ---------------- setup ----------------

__global__ void pmap_kernel(const int* __restrict__ batch, int* __restrict__ pmap, int N) {
    int v = blockIdx.x * blockDim.x + threadIdx.x;
    if (v >= N) return;
    int b = batch[v];
    int prev = (v == 0) ? -1 : batch[v - 1];
    pmap[v] = (b != prev) ? (b + 1) : 0;
}

__global__ void compute_idx_kernel(const int* __restrict__ batch, int* __restrict__ idx,
                                   int N, int G) {
    int g = blockIdx.x * blockDim.x + threadIdx.x;
    if (g >= G) return;
    int lo = 0, hi = N;
    while (lo < hi) {
        int mid = (lo + hi) >> 1;
        if (batch[mid] < g) lo = mid + 1; else hi = mid;
    }
    idx[g] = lo;
}

// ---------------- radix-partition CSR build ----------------

__global__ void bucket_hist_kernel(const int* __restrict__ ei, int* __restrict__ bucketTot,
                                   long long E, int K) {
    __shared__ int hist[KMAX];
    for (int b = threadIdx.x; b < K; b += blockDim.x) hist[b] = 0;
    __syncthreads();
    long long tid = (long long)blockIdx.x * blockDim.x + threadIdx.x;
    long long stride = (long long)gridDim.x * blockDim.x;
    for (long long e = tid; e < E; e += stride) {
        int d = ei[E + e];
        atomicAdd(&hist[d >> RSHIFT], 1);
    }
    __syncthreads();
    for (int b = threadIdx.x; b < K; b += blockDim.x) {
        int h = hist[b];
        if (h) atomicAdd(&bucketTot[b], h);
    }
}

__global__ void bucket_scan_kernel(const int* __restrict__ bucketTot, int* __restrict__ bucketStart,
                                   int* __restrict__ bucketCursor, int K, int Etot,
                                   int* __restrict__ rowptr, int N) {
    __shared__ int s[KMAX];
    int t = threadIdx.x;
    int v = (t < K) ? bucketTot[t] : 0;
    s[t] = v;
    __syncthreads();
    for (int off = 1; off < KMAX; off <<= 1) {
        int tmp = (t >= off) ? s[t - off] : 0;
        __syncthreads();
        s[t] += tmp;
        __syncthreads();
    }
    if (t < K) {
        int excl = s[t] - v;
        bucketStart[t] = excl;
        bucketCursor[t] = excl;
    }
    if (t == 0) {
        bucketStart[K] = Etot;
        rowptr[N] = Etot;
    }
}

__global__ void partition_kernel(const int* __restrict__ ei, int* __restrict__ bucketCursor,
                                 unsigned int* __restrict__ pairs, long long E, int K) {
    __shared__ int hist[KMAX];
    __shared__ int off[KMAX];
    __shared__ int cur[KMAX];
    int t = threadIdx.x;
    for (int b = t; b < K; b += blockDim.x) { hist[b] = 0; cur[b] = 0; }
    __syncthreads();
    long long e0 = (long long)blockIdx.x * PART_CH;
    int cnt = (int)min((long long)PART_CH, E - e0);
    for (int i = t; i < cnt; i += blockDim.x) {
        int d = ei[E + e0 + i];
        atomicAdd(&hist[d >> RSHIFT], 1);
    }
    __syncthreads();
    for (int b = t; b < K; b += blockDim.x) {
        int h = hist[b];
        off[b] = h ? atomicAdd(&bucketCursor[b], h) : 0;
    }
    __syncthreads();
    for (int i = t; i < cnt; i += blockDim.x) {
        long long e = e0 + i;
        unsigned int s = (unsigned int)ei[e];
        int d = ei[E + e];
        int b = d >> RSHIFT;
        int p = off[b] + atomicAdd(&cur[b], 1);
        pairs[p] = (s << RSHIFT) | (unsigned int)(d & (RANGE - 1));
    }
}

__global__ void build_csr_kernel(const unsigned int* __restrict__ pairs,
                                 const int* __restrict__ bucketStart,
                                 int* __restrict__ rowptr, float* __restrict__ dinv,
                                 int* __restrict__ csr_src, int N) {
    __shared__ int hist[RANGE];
    __shared__ int scanb[RANGE];
    __shared__ int cursor[RANGE];
    int b = blockIdx.x;
    int t = threadIdx.x;
    int base = b << RSHIFT;
    int s0 = bucketStart[b];
    int s1 = bucketStart[b + 1];
    int cnt = s1 - s0;
    hist[t] = 0;
    __syncthreads();
    for (int i = t; i < cnt; i += RANGE) {
        unsigned int p = pairs[s0 + i];
        atomicAdd(&hist[p & (RANGE - 1)], 1);
    }
    __syncthreads();
    int deg = hist[t];
    scanb[t] = deg;
    __syncthreads();
    for (int off = 1; off < RANGE; off <<= 1) {
        int tmp = (t >= off) ? scanb[t - off] : 0;
        __syncthreads();
        scanb[t] += tmp;
        __syncthreads();
    }
    int excl = scanb[t] - deg;
    int node = base + t;
    if (node < N) {
        rowptr[node] = s0 + excl;
        dinv[node] = rsqrtf((float)(deg + 1));   // +1 self-loop
    }
    cursor[t] = s0 + excl;
    __syncthreads();
    for (int i = t; i < cnt; i += RANGE) {
        unsigned int p = pairs[s0 + i];
        int slot = atomicAdd(&cursor[p & (RANGE - 1)], 1);
        csr_src[slot] = (int)(p >> RSHIFT);
    }
}

// ---------------- input transform: tp1 = (x@W1)*dinv, bf16, quarter-major ----------------
// tp layout: [q][N][8] so each quarter slice is a CONTIGUOUS 3.2 MB block
// (round-8 lesson: logical slicing without physical layout change kept the
//  L2 working set at 12.8 MB — cache lines span all four quarters).

__global__ void gemm_in_kernel(const float* __restrict__ x, const float* __restrict__ W,
                               const float* __restrict__ dinv, u16* __restrict__ tp, int N) {
    __shared__ float Wl[IN_DIM * LAT];         // 16 KB
    __shared__ float Xl[GIN_ROWS * IN_DIM];    // 16 KB
    int t = threadIdx.x;
    for (int i = t; i < IN_DIM * LAT; i += 256) Wl[i] = W[i];
    long long rowBase = (long long)blockIdx.x * GIN_ROWS;
    int nrow = min(GIN_ROWS, (int)(N - rowBase));
    {
        const float4* x4 = reinterpret_cast<const float4*>(x + rowBase * IN_DIM);
        float4* X4 = reinterpret_cast<float4*>(Xl);
        int nf4 = nrow * (IN_DIM / 4);
        for (int i = t; i < nf4; i += 256) X4[i] = x4[i];   // coalesced
    }
    __syncthreads();
    int g = t >> 5;            // col-group 0..7
    int c = t & 31;
    int r0 = g * 4;            // 4 local rows per group
    float acc0 = 0.f, acc1 = 0.f, acc2 = 0.f, acc3 = 0.f;
#pragma unroll 4
    for (int k = 0; k < IN_DIM; k += 4) {
        float w0 = Wl[(k + 0) * LAT + c];
        float w1 = Wl[(k + 1) * LAT + c];
        float w2 = Wl[(k + 2) * LAT + c];
        float w3 = Wl[(k + 3) * LAT + c];
        float4 xa = *reinterpret_cast<const float4*>(&Xl[(r0 + 0) * IN_DIM + k]);
        float4 xb = *reinterpret_cast<const float4*>(&Xl[(r0 + 1) * IN_DIM + k]);
        float4 xc = *reinterpret_cast<const float4*>(&Xl[(r0 + 2) * IN_DIM + k]);
        float4 xd = *reinterpret_cast<const float4*>(&Xl[(r0 + 3) * IN_DIM + k]);
        acc0 += xa.x * w0 + xa.y * w1 + xa.z * w2 + xa.w * w3;
        acc1 += xb.x * w0 + xb.y * w1 + xb.z * w2 + xb.w * w3;
        acc2 += xc.x * w0 + xc.y * w1 + xc.z * w2 + xc.w * w3;
        acc3 += xd.x * w0 + xd.y * w1 + xd.z * w2 + xd.w * w3;
    }
    long long rr = rowBase + r0;
    size_t NS = (size_t)N * 8;
    size_t qoff = (size_t)(c >> 3) * NS + (c & 7);
    if (r0 + 0 < nrow) tp[qoff + (rr + 0) * 8] = f2bf(acc0 * dinv[rr + 0]);
    if (r0 + 1 < nrow) tp[qoff + (rr + 1) * 8] = f2bf(acc1 * dinv[rr + 1]);
    if (r0 + 2 < nrow) tp[qoff + (rr + 2) * 8] = f2bf(acc2 * dinv[rr + 2]);
    if (r0 + 3 < nrow) tp[qoff + (rr + 3) * 8] = f2bf(acc3 * dinv[rr + 3]);
}

// ---------------- feature-quarter gather + tanh ----------------
// Pass q gathers from contiguous slice tp+q*N*8 (3.2 MB, per-XCD L2-resident).
// Wave = 2 nodes (32 edge-lanes each); lane = 1 edge, 16B contiguous load.
// Index stream + h output are nontemporal to protect the resident slice.

__global__ void gather_q_kernel(const int* __restrict__ rowptr, const int* __restrict__ csr_src,
                                const u16* __restrict__ tp, const float* __restrict__ dinv,
                                const float* __restrict__ bcur, const int* __restrict__ pmap,
                                float* __restrict__ pooled, int colOff, int q,
                                u16* __restrict__ hq, const int* __restrict__ vmap,
                                int Nv, int N) {
    int wv = threadIdx.x >> 6;
    int lane = threadIdx.x & 63;
    int slot = lane & 31;
    int vi = (blockIdx.x * 4 + wv) * 2 + (lane >> 5);
    bool vok = vi < Nv;
    int v = 0;
    if (vok) v = vmap ? vmap[vi] : vi;
    int start = 0, end = 0;
    if (vok) { start = rowptr[v]; end = rowptr[v + 1]; }
    int deg = end - start;
    int iters = (deg + 31) >> 5;
    int itA = __shfl(iters, 0, 64);
    int itB = __shfl(iters, 32, 64);
    int itW = itA > itB ? itA : itB;

    float c0 = 0.f, c1 = 0.f, c2 = 0.f, c3 = 0.f,
          c4 = 0.f, c5 = 0.f, c6 = 0.f, c7 = 0.f;
    const u16* tq = tp + (size_t)q * N * 8;
    for (int k = 0; k < itW; ++k) {
        int e = start + slot + (k << 5);
        if (e < end) {
            int sj = __builtin_nontemporal_load(csr_src + e);
            const uint4 w = *reinterpret_cast<const uint4*>(tq + ((size_t)sj << 3));
            c0 += bflo(w.x); c1 += bfhi(w.x);
            c2 += bflo(w.y); c3 += bfhi(w.y);
            c4 += bflo(w.z); c5 += bfhi(w.z);
            c6 += bflo(w.w); c7 += bfhi(w.w);
        }
    }
    if (slot == 0 && vok) {   // self-loop term
        const uint4 w = *reinterpret_cast<const uint4*>(tq + ((size_t)v << 3));
        c0 += bflo(w.x); c1 += bfhi(w.x);
        c2 += bflo(w.y); c3 += bfhi(w.y);
        c4 += bflo(w.z); c5 += bfhi(w.z);
        c6 += bflo(w.w); c7 += bfhi(w.w);
    }
#pragma unroll
    for (int d = 1; d <= 16; d <<= 1) {   // allreduce within each 32-half
        c0 += __shfl_xor(c0, d, 64); c1 += __shfl_xor(c1, d, 64);
        c2 += __shfl_xor(c2, d, 64); c3 += __shfl_xor(c3, d, 64);
        c4 += __shfl_xor(c4, d, 64); c5 += __shfl_xor(c5, d, 64);
        c6 += __shfl_xor(c6, d, 64); c7 += __shfl_xor(c7, d, 64);
    }
    if (!vok) return;
    int j = slot & 7;
    float sv = (j < 4) ? ((j < 2) ? (j == 0 ? c0 : c1) : (j == 2 ? c2 : c3))
                       : ((j < 6) ? (j == 4 ? c4 : c5) : (j == 6 ? c6 : c7));
    float dv = dinv[v];
    float hv = tanhf(dv * sv + bcur[(q << 3) + j]);
    if (slot < 8) {
        if (hq) __builtin_nontemporal_store(f2bf(hv),
                    hq + (size_t)q * N * 8 + ((size_t)v << 3) + j);
        int pg = pmap[v];
        if (pg) pooled[(size_t)(pg - 1) * (3 * LAT) + colOff + (q << 3) + j] = hv;
    }
}

// ---------------- latent GEMM: tp = (h @ W) * dinv, bf16 quarter-major in/out ----------------

__global__ void gemm_lat_kernel(const u16* __restrict__ h, const float* __restrict__ W,
                                const float* __restrict__ dinv, u16* __restrict__ tp, int N) {
    __shared__ float Wl[LAT * LAT];
    for (int i = threadIdx.x; i < LAT * LAT; i += 256) Wl[i] = W[i];
    __syncthreads();
    int gid = blockIdx.x * 256 + threadIdx.x;
    if (gid >= N * LAT) return;
    int v = gid >> 5, c = gid & 31;
    size_t NS = (size_t)N * 8;
    float acc = 0.f;
    int kk = 0;
#pragma unroll
    for (int q = 0; q < 4; q++) {
        const uint4 a = *reinterpret_cast<const uint4*>(h + q * NS + ((size_t)v << 3));
        acc += bflo(a.x) * Wl[kk * LAT + c] + bfhi(a.x) * Wl[(kk + 1) * LAT + c];
        acc += bflo(a.y) * Wl[(kk + 2) * LAT + c] + bfhi(a.y) * Wl[(kk + 3) * LAT + c];
        acc += bflo(a.z) * Wl[(kk + 4) * LAT + c] + bfhi(a.z) * Wl[(kk + 5) * LAT + c];
        acc += bflo(a.w) * Wl[(kk + 6) * LAT + c] + bfhi(a.w) * Wl[(kk + 7) * LAT + c];
        kk += 8;
    }
    tp[(size_t)(c >> 3) * NS + ((size_t)v << 3) + (c & 7)] = f2bf(acc * dinv[v]);
}

// ---------------- MLP head ----------------

__global__ void mlp_head_kernel(const float* __restrict__ pooled,
                                const float* __restrict__ Wl1, const float* __restrict__ bl1,
                                const float* __restrict__ Wl2, const float* __restrict__ bl2,
                                float* __restrict__ out, int G) {
    __shared__ float prow[3 * LAT];
    __shared__ float red0[HID];
    __shared__ float red1[HID];
    int g = blockIdx.x;
    int j = threadIdx.x;
    if (j < 3 * LAT) prow[j] = pooled[(long long)g * (3 * LAT) + j];
    __syncthreads();
    float acc = bl1[j];
#pragma unroll 8
    for (int k = 0; k < 3 * LAT; k++) acc += prow[k] * Wl1[k * HID + j];
    float hj = fmaxf(acc, 0.f);
    red0[j] = hj * Wl2[j * 2 + 0];
    red1[j] = hj * Wl2[j * 2 + 1];
    __syncthreads();
    for (int s = HID / 2; s > 0; s >>= 1) {
        if (j < s) { red0[j] += red0[j + s]; red1[j] += red1[j + s]; }
        __syncthreads();
    }
    if (j == 0) {
        float l0 = red0[0] + bl2[0];
        float l1 = red1[0] + bl2[1];
        float m = fmaxf(l0, l1);
        float lse = m + logf(expf(l0 - m) + expf(l1 - m));
        out[(long long)g * 2 + 0] = l0 - lse;
        out[(long long)g * 2 + 1] = l1 - lse;
    }
}

// ---------------- launch ----------------

extern "C" void kernel_launch(void* const* d_in, const int* in_sizes, int n_in,
                              void* d_out, int out_size, void* d_ws, size_t ws_size,
                              hipStream_t stream) {
    const float* x    = (const float*)d_in[0];
    const int*   ei   = (const int*)d_in[1];
    const int*   batch= (const int*)d_in[2];
    const float* W1   = (const float*)d_in[3];
    const float* b1   = (const float*)d_in[4];
    const float* W2   = (const float*)d_in[5];
    const float* b2   = (const float*)d_in[6];
    const float* W3   = (const float*)d_in[7];
    const float* b3   = (const float*)d_in[8];
    const float* Wl1  = (const float*)d_in[9];
    const float* bl1  = (const float*)d_in[10];
    const float* Wl2  = (const float*)d_in[11];
    const float* bl2  = (const float*)d_in[12];
    float* out = (float*)d_out;

    const int N = in_sizes[2];
    const long long E = (long long)in_sizes[1] / 2;
    const int G = out_size / 2;
    const int K = (N + RANGE - 1) >> RSHIFT;

    // workspace layout
    char* ws = (char*)d_ws;
    size_t off = 0;
    char*  regionA = ws + off;           off += (size_t)E * 4;   // pairs; later tpA(12.8M)+hbuf(12.8M)
    char*  bufB    = ws + off;           off += (size_t)N * LAT * 2;
    int*   csr_src = (int*)  (ws + off); off += (size_t)E * 4;
    float* dinv    = (float*)(ws + off); off += (size_t)N * 4;
    int*   rowptr  = (int*)  (ws + off); off += (size_t)(N + 1) * 4;
    int*   pmap    = (int*)  (ws + off); off += (size_t)N * 4;
    int*   idx     = (int*)  (ws + off); off += (size_t)G * 4;
    float* pooled  = (float*)(ws + off); off += (size_t)G * (3 * LAT) * 4;
    int*   bucketTot    = (int*)(ws + off); off += (KMAX + 1) * 4;
    int*   bucketStart  = (int*)(ws + off); off += (KMAX + 1) * 4;
    int*   bucketCursor = (int*)(ws + off); off += KMAX * 4;

    unsigned int* pairs = (unsigned int*)regionA;        // dead before gemm_in writes tpA
    u16* tpA  = (u16*)regionA;                            // [4][N][8] bf16 = 12.8 MB
    u16* hbuf = (u16*)(regionA + (size_t)N * LAT * 2);    // [4][N][8] bf16 = 12.8 MB
    u16* tpB  = (u16*)bufB;

    const int BS = 256;
    const int gqBlocks  = (N + 7) / 8;                   // wave = 2 nodes, 4 waves/block
    const int gq3Blocks = (G + 7) / 8;
    const int nvBlocks  = (N * LAT + BS - 1) / BS;
    const int ginBlocks = (N + GIN_ROWS - 1) / GIN_ROWS;
    const int partBlocks = (int)((E + PART_CH - 1) / PART_CH);

    // ---- CSR build via radix partition ----
    hipMemsetAsync(bucketTot, 0, (size_t)(KMAX + 1) * 4, stream);
    pmap_kernel<<<(N + BS - 1) / BS, BS, 0, stream>>>(batch, pmap, N);
    compute_idx_kernel<<<(G + BS - 1) / BS, BS, 0, stream>>>(batch, idx, N, G);
    bucket_hist_kernel<<<256, BS, 0, stream>>>(ei, bucketTot, E, K);
    bucket_scan_kernel<<<1, KMAX, 0, stream>>>(bucketTot, bucketStart, bucketCursor, K, (int)E, rowptr, N);
    partition_kernel<<<partBlocks, BS, 0, stream>>>(ei, bucketCursor, pairs, E, K);
    build_csr_kernel<<<K, RANGE, 0, stream>>>(pairs, bucketStart, rowptr, dinv, csr_src, N);

    // ---- layer 1 transform ----
    gemm_in_kernel<<<ginBlocks, BS, 0, stream>>>(x, W1, dinv, tpA, N);

    // ---- layer 1: 4 feature-quarter gathers (tpA -> hbuf), then tp2 = (h@W2)*dinv ----
    for (int q = 0; q < 4; q++)
        gather_q_kernel<<<gqBlocks, BS, 0, stream>>>(rowptr, csr_src, tpA, dinv, b1, pmap,
                                                     pooled, 0, q, hbuf, (const int*)nullptr, N, N);
    gemm_lat_kernel<<<nvBlocks, BS, 0, stream>>>(hbuf, W2, dinv, tpB, N);

    // ---- layer 2: (tpB -> hbuf), then tp3 = (h@W3)*dinv ----
    for (int q = 0; q < 4; q++)
        gather_q_kernel<<<gqBlocks, BS, 0, stream>>>(rowptr, csr_src, tpB, dinv, b2, pmap,
                                                     pooled, LAT, q, hbuf, (const int*)nullptr, N, N);
    gemm_lat_kernel<<<nvBlocks, BS, 0, stream>>>(hbuf, W3, dinv, tpA, N);

    // ---- layer 3: h3 only needed at the G readout nodes ----
    for (int q = 0; q < 4; q++)
        gather_q_kernel<<<gq3Blocks, BS, 0, stream>>>(rowptr, csr_src, tpA, dinv, b3, pmap,
                                                      pooled, 2 * LAT, q, (u16*)nullptr, idx, G, N);

    // ---- MLP head ----
    mlp_head_kernel<<<G, HID, 0, stream>>>(pooled, Wl1, bl1, Wl2, bl2, out, G);
}

// Round 10
// 662.651 us; speedup vs baseline: 1.6317x; 1.4121x over previous
//
#include <hip/hip_runtime.h>
#include <hip/hip_bf16.h>
#include <math.h>

#define IN_DIM 128
#define LAT 32
#define HID 128
#define RSHIFT 8          // nodes per bucket = 256
#define RANGE 256
#define KMAX 1024
#define PART_CH 12288     // LDS-staged counting sort: 48KB stage + 13KB tables
#define GIN_ROWS 32       // rows per block in gemm_in

typedef unsigned short u16;

__device__ __forceinline__ float bf2f(u16 v) {
    return __uint_as_float(((unsigned int)v) << 16);
}
__device__ __forceinline__ u16 f2bf(float f) {
    unsigned int u = __float_as_uint(f);
    u += 0x7fff + ((u >> 16) & 1);   // round-to-nearest-even
    return (u16)(u >> 16);
}

// ---------------- setup ----------------

__global__ void pmap_kernel(const int* __restrict__ batch, int* __restrict__ pmap, int N) {
    int v = blockIdx.x * blockDim.x + threadIdx.x;
    if (v >= N) return;
    int b = batch[v];
    int prev = (v == 0) ? -1 : batch[v - 1];
    pmap[v] = (b != prev) ? (b + 1) : 0;
}

__global__ void compute_idx_kernel(const int* __restrict__ batch, int* __restrict__ idx,
                                   int N, int G) {
    int g = blockIdx.x * blockDim.x + threadIdx.x;
    if (g >= G) return;
    int lo = 0, hi = N;
    while (lo < hi) {
        int mid = (lo + hi) >> 1;
        if (batch[mid] < g) lo = mid + 1; else hi = mid;
    }
    idx[g] = lo;
}

// ---------------- radix-partition CSR build ----------------

__global__ void bucket_hist_kernel(const int* __restrict__ ei, int* __restrict__ bucketTot,
                                   long long E, int K) {
    __shared__ int hist[KMAX];
    for (int b = threadIdx.x; b < K; b += blockDim.x) hist[b] = 0;
    __syncthreads();
    long long tid = (long long)blockIdx.x * blockDim.x + threadIdx.x;
    long long stride = (long long)gridDim.x * blockDim.x;
    for (long long e = tid; e < E; e += stride) {
        int d = ei[E + e];
        atomicAdd(&hist[d >> RSHIFT], 1);
    }
    __syncthreads();
    for (int b = threadIdx.x; b < K; b += blockDim.x) {
        int h = hist[b];
        if (h) atomicAdd(&bucketTot[b], h);
    }
}

__global__ void bucket_scan_kernel(const int* __restrict__ bucketTot, int* __restrict__ bucketStart,
                                   int* __restrict__ bucketCursor, int K, int Etot,
                                   int* __restrict__ rowptr, int N) {
    __shared__ int s[KMAX];
    int t = threadIdx.x;
    int v = (t < K) ? bucketTot[t] : 0;
    s[t] = v;
    __syncthreads();
    for (int off = 1; off < KMAX; off <<= 1) {
        int tmp = (t >= off) ? s[t - off] : 0;
        __syncthreads();
        s[t] += tmp;
        __syncthreads();
    }
    if (t < K) {
        int excl = s[t] - v;
        bucketStart[t] = excl;
        bucketCursor[t] = excl;
    }
    if (t == 0) {
        bucketStart[K] = Etot;
        rowptr[N] = Etot;
    }
}

// Block-local LDS counting sort, then contiguous per-bucket run flushes.
// (round-9 lesson: direct scattered frontier writes amplified 25.6MB payload
//  to 152-189MB HBM writes; sorted runs flush as full coalesced lines)
__global__ void partition_kernel(const int* __restrict__ ei, int* __restrict__ bucketCursor,
                                 unsigned int* __restrict__ pairs, long long E, int K) {
    __shared__ unsigned int stage[PART_CH];   // 48KB
    __shared__ int histS[KMAX];               // counts -> exclusive local offsets
    __shared__ int curS[KMAX];
    __shared__ int gbase[KMAX];
    __shared__ int tsum[256];
    int t = threadIdx.x;
    for (int b = t; b < KMAX; b += 256) histS[b] = 0;
    __syncthreads();
    long long e0 = (long long)blockIdx.x * PART_CH;
    int cnt = (int)min((long long)PART_CH, E - e0);
    for (int i = t; i < cnt; i += 256) {
        int d = ei[E + e0 + i];
        atomicAdd(&histS[d >> RSHIFT], 1);
    }
    __syncthreads();
    // reserve global frontier space per bucket
    for (int b = t; b < K; b += 256) {
        int h = histS[b];
        gbase[b] = h ? atomicAdd(&bucketCursor[b], h) : 0;
    }
    // exclusive scan of histS (KMAX entries, 4 per thread)
    int h0 = histS[4 * t + 0], h1 = histS[4 * t + 1],
        h2 = histS[4 * t + 2], h3 = histS[4 * t + 3];
    int sum = h0 + h1 + h2 + h3;
    tsum[t] = sum;
    __syncthreads();
    for (int off = 1; off < 256; off <<= 1) {
        int v = (t >= off) ? tsum[t - off] : 0;
        __syncthreads();
        tsum[t] += v;
        __syncthreads();
    }
    int base = tsum[t] - sum;
    histS[4 * t + 0] = base;
    histS[4 * t + 1] = base + h0;
    histS[4 * t + 2] = base + h0 + h1;
    histS[4 * t + 3] = base + h0 + h1 + h2;
    curS[4 * t + 0] = base;
    curS[4 * t + 1] = base + h0;
    curS[4 * t + 2] = base + h0 + h1;
    curS[4 * t + 3] = base + h0 + h1 + h2;
    __syncthreads();
    // scatter into LDS stage (sorted by bucket)
    for (int i = t; i < cnt; i += 256) {
        long long e = e0 + i;
        unsigned int s = (unsigned int)ei[e];
        int d = ei[E + e];
        int b = d >> RSHIFT;
        int p = atomicAdd(&curS[b], 1);
        stage[p] = (s << RSHIFT) | (unsigned int)(d & (RANGE - 1));
    }
    __syncthreads();
    // flush: consecutive threads write consecutive positions -> coalesced runs
    for (int i = t; i < cnt; i += 256) {
        int lo = 0, hi = K - 1;
        while (lo < hi) {                      // last b with lofs[b] <= i
            int mid = (lo + hi + 1) >> 1;
            if (histS[mid] <= i) lo = mid; else hi = mid - 1;
        }
        pairs[(long long)gbase[lo] + (i - histS[lo])] = stage[i];
    }
}

__global__ void build_csr_kernel(const unsigned int* __restrict__ pairs,
                                 const int* __restrict__ bucketStart,
                                 int* __restrict__ rowptr, float* __restrict__ dinv,
                                 int* __restrict__ csr_src, int N) {
    __shared__ int hist[RANGE];
    __shared__ int scanb[RANGE];
    __shared__ int cursor[RANGE];
    int b = blockIdx.x;
    int t = threadIdx.x;
    int base = b << RSHIFT;
    int s0 = bucketStart[b];
    int s1 = bucketStart[b + 1];
    int cnt = s1 - s0;
    hist[t] = 0;
    __syncthreads();
    for (int i = t; i < cnt; i += RANGE) {
        unsigned int p = pairs[s0 + i];
        atomicAdd(&hist[p & (RANGE - 1)], 1);
    }
    __syncthreads();
    int deg = hist[t];
    scanb[t] = deg;
    __syncthreads();
    for (int off = 1; off < RANGE; off <<= 1) {
        int tmp = (t >= off) ? scanb[t - off] : 0;
        __syncthreads();
        scanb[t] += tmp;
        __syncthreads();
    }
    int excl = scanb[t] - deg;
    int node = base + t;
    if (node < N) {
        rowptr[node] = s0 + excl;
        dinv[node] = rsqrtf((float)(deg + 1));   // +1 self-loop
    }
    cursor[t] = s0 + excl;
    __syncthreads();
    for (int i = t; i < cnt; i += RANGE) {
        unsigned int p = pairs[s0 + i];
        int slot = atomicAdd(&cursor[p & (RANGE - 1)], 1);
        csr_src[slot] = (int)(p >> RSHIFT);
    }
}

// ---------------- input transform: tp1 = (x@W1)*dinv, bf16 row-major ----------------

__global__ void gemm_in_kernel(const float* __restrict__ x, const float* __restrict__ W,
                               const float* __restrict__ dinv, u16* __restrict__ tp, int N) {
    __shared__ float Wl[IN_DIM * LAT];         // 16 KB
    __shared__ float Xl[GIN_ROWS * IN_DIM];    // 16 KB
    int t = threadIdx.x;
    for (int i = t; i < IN_DIM * LAT; i += 256) Wl[i] = W[i];
    long long rowBase = (long long)blockIdx.x * GIN_ROWS;
    int nrow = min(GIN_ROWS, (int)(N - rowBase));
    {
        const float4* x4 = reinterpret_cast<const float4*>(x + rowBase * IN_DIM);
        float4* X4 = reinterpret_cast<float4*>(Xl);
        int nf4 = nrow * (IN_DIM / 4);
        for (int i = t; i < nf4; i += 256) X4[i] = x4[i];   // coalesced
    }
    __syncthreads();
    int g = t >> 5;            // col-group 0..7
    int c = t & 31;
    int r0 = g * 4;            // 4 local rows per group
    float acc0 = 0.f, acc1 = 0.f, acc2 = 0.f, acc3 = 0.f;
#pragma unroll 4
    for (int k = 0; k < IN_DIM; k += 4) {
        float w0 = Wl[(k + 0) * LAT + c];
        float w1 = Wl[(k + 1) * LAT + c];
        float w2 = Wl[(k + 2) * LAT + c];
        float w3 = Wl[(k + 3) * LAT + c];
        float4 xa = *reinterpret_cast<const float4*>(&Xl[(r0 + 0) * IN_DIM + k]);
        float4 xb = *reinterpret_cast<const float4*>(&Xl[(r0 + 1) * IN_DIM + k]);
        float4 xc = *reinterpret_cast<const float4*>(&Xl[(r0 + 2) * IN_DIM + k]);
        float4 xd = *reinterpret_cast<const float4*>(&Xl[(r0 + 3) * IN_DIM + k]);
        acc0 += xa.x * w0 + xa.y * w1 + xa.z * w2 + xa.w * w3;
        acc1 += xb.x * w0 + xb.y * w1 + xb.z * w2 + xb.w * w3;
        acc2 += xc.x * w0 + xc.y * w1 + xc.z * w2 + xc.w * w3;
        acc3 += xd.x * w0 + xd.y * w1 + xd.z * w2 + xd.w * w3;
    }
    long long rr = rowBase + r0;
    if (r0 + 0 < nrow) tp[(rr + 0) * LAT + c] = f2bf(acc0 * dinv[rr + 0]);
    if (r0 + 1 < nrow) tp[(rr + 1) * LAT + c] = f2bf(acc1 * dinv[rr + 1]);
    if (r0 + 2 < nrow) tp[(rr + 2) * LAT + c] = f2bf(acc2 * dinv[rr + 2]);
    if (r0 + 3 < nrow) tp[(rr + 3) * LAT + c] = f2bf(acc3 * dinv[rr + 3]);
}

// ---------------- fused gather + tanh + next-layer GEMM ----------------
// Round-5 geometry (best measured: 1 line-transaction per edge, 8-deep MLP,
// VGPR ~20 -> ~80% occupancy). h never materialized: pooled + tpNext only.

__global__ void gather_fused_kernel(const int* __restrict__ rowptr, const int* __restrict__ csr_src,
                                    const u16* __restrict__ tp, const float* __restrict__ dinv,
                                    const float* __restrict__ bcur, const int* __restrict__ pmap,
                                    float* __restrict__ pooled, int colOff,
                                    const float* __restrict__ Wnext, u16* __restrict__ tpNext,
                                    int N) {
    __shared__ float Wl[LAT * LAT];
    for (int i = threadIdx.x; i < LAT * LAT; i += blockDim.x) Wl[i] = Wnext[i];
    __syncthreads();
    int v = blockIdx.x * 8 + (int)(threadIdx.x >> 5);
    int f = threadIdx.x & 31;
    if (v >= N) return;
    int start = rowptr[v];
    int end = rowptr[v + 1];
    float acc = bf2f(tp[(long long)v * LAT + f]);   // self-loop term
    int e = start;
    for (; e + 32 <= end; e += 32) {
        int s = csr_src[e + f];                     // coalesced index load
#pragma unroll
        for (int jj = 0; jj < 32; jj += 8) {
            int s0 = __shfl(s, jj + 0, 32), s1 = __shfl(s, jj + 1, 32);
            int s2 = __shfl(s, jj + 2, 32), s3 = __shfl(s, jj + 3, 32);
            int s4 = __shfl(s, jj + 4, 32), s5 = __shfl(s, jj + 5, 32);
            int s6 = __shfl(s, jj + 6, 32), s7 = __shfl(s, jj + 7, 32);
            float r0 = bf2f(tp[(long long)s0 * LAT + f]);
            float r1 = bf2f(tp[(long long)s1 * LAT + f]);
            float r2 = bf2f(tp[(long long)s2 * LAT + f]);
            float r3 = bf2f(tp[(long long)s3 * LAT + f]);
            float r4 = bf2f(tp[(long long)s4 * LAT + f]);
            float r5 = bf2f(tp[(long long)s5 * LAT + f]);
            float r6 = bf2f(tp[(long long)s6 * LAT + f]);
            float r7 = bf2f(tp[(long long)s7 * LAT + f]);
            acc += ((r0 + r1) + (r2 + r3)) + ((r4 + r5) + (r6 + r7));
        }
    }
    int rem = end - e;
    if (rem > 0) {
        int s = (f < rem) ? csr_src[e + f] : 0;
        int j = 0;
        for (; j + 4 <= rem; j += 4) {
            int s0 = __shfl(s, j + 0, 32), s1 = __shfl(s, j + 1, 32);
            int s2 = __shfl(s, j + 2, 32), s3 = __shfl(s, j + 3, 32);
            float r0 = bf2f(tp[(long long)s0 * LAT + f]);
            float r1 = bf2f(tp[(long long)s1 * LAT + f]);
            float r2 = bf2f(tp[(long long)s2 * LAT + f]);
            float r3 = bf2f(tp[(long long)s3 * LAT + f]);
            acc += (r0 + r1) + (r2 + r3);
        }
        for (; j < rem; j++) {
            int sj = __shfl(s, j, 32);
            acc += bf2f(tp[(long long)sj * LAT + f]);
        }
    }
    float dv = dinv[v];
    float hv = tanhf(dv * acc + bcur[f]);
    int pg = pmap[v];
    if (pg) pooled[(long long)(pg - 1) * (3 * LAT) + colOff + f] = hv;
    float acc2 = 0.f;
#pragma unroll
    for (int k = 0; k < LAT; k++) acc2 += __shfl(hv, k, 32) * Wl[k * LAT + f];
    tpNext[(long long)v * LAT + f] = f2bf(acc2 * dv);
}

// ---------------- layer-3 gather: only the G readout nodes ----------------

__global__ void gather_readout_kernel(const int* __restrict__ rowptr, const int* __restrict__ csr_src,
                                      const u16* __restrict__ tp, const float* __restrict__ dinv,
                                      const float* __restrict__ bcur, const int* __restrict__ idx,
                                      float* __restrict__ pooled, int colOff, int G) {
    int vi = blockIdx.x * 8 + (int)(threadIdx.x >> 5);
    int f = threadIdx.x & 31;
    if (vi >= G) return;
    int v = idx[vi];
    int start = rowptr[v];
    int end = rowptr[v + 1];
    float acc = bf2f(tp[(long long)v * LAT + f]);
    int e = start;
    for (; e + 32 <= end; e += 32) {
        int s = csr_src[e + f];
#pragma unroll
        for (int jj = 0; jj < 32; jj += 8) {
            int s0 = __shfl(s, jj + 0, 32), s1 = __shfl(s, jj + 1, 32);
            int s2 = __shfl(s, jj + 2, 32), s3 = __shfl(s, jj + 3, 32);
            int s4 = __shfl(s, jj + 4, 32), s5 = __shfl(s, jj + 5, 32);
            int s6 = __shfl(s, jj + 6, 32), s7 = __shfl(s, jj + 7, 32);
            float r0 = bf2f(tp[(long long)s0 * LAT + f]);
            float r1 = bf2f(tp[(long long)s1 * LAT + f]);
            float r2 = bf2f(tp[(long long)s2 * LAT + f]);
            float r3 = bf2f(tp[(long long)s3 * LAT + f]);
            float r4 = bf2f(tp[(long long)s4 * LAT + f]);
            float r5 = bf2f(tp[(long long)s5 * LAT + f]);
            float r6 = bf2f(tp[(long long)s6 * LAT + f]);
            float r7 = bf2f(tp[(long long)s7 * LAT + f]);
            acc += ((r0 + r1) + (r2 + r3)) + ((r4 + r5) + (r6 + r7));
        }
    }
    int rem = end - e;
    if (rem > 0) {
        int s = (f < rem) ? csr_src[e + f] : 0;
        for (int j = 0; j < rem; j++) {
            int sj = __shfl(s, j, 32);
            acc += bf2f(tp[(long long)sj * LAT + f]);
        }
    }
    float hv = tanhf(dinv[v] * acc + bcur[f]);
    pooled[(long long)vi * (3 * LAT) + colOff + f] = hv;
}

// ---------------- MLP head ----------------

__global__ void mlp_head_kernel(const float* __restrict__ pooled,
                                const float* __restrict__ Wl1, const float* __restrict__ bl1,
                                const float* __restrict__ Wl2, const float* __restrict__ bl2,
                                float* __restrict__ out, int G) {
    __shared__ float prow[3 * LAT];
    __shared__ float red0[HID];
    __shared__ float red1[HID];
    int g = blockIdx.x;
    int j = threadIdx.x;
    if (j < 3 * LAT) prow[j] = pooled[(long long)g * (3 * LAT) + j];
    __syncthreads();
    float acc = bl1[j];
#pragma unroll 8
    for (int k = 0; k < 3 * LAT; k++) acc += prow[k] * Wl1[k * HID + j];
    float hj = fmaxf(acc, 0.f);
    red0[j] = hj * Wl2[j * 2 + 0];
    red1[j] = hj * Wl2[j * 2 + 1];
    __syncthreads();
    for (int s = HID / 2; s > 0; s >>= 1) {
        if (j < s) { red0[j] += red0[j + s]; red1[j] += red1[j + s]; }
        __syncthreads();
    }
    if (j == 0) {
        float l0 = red0[0] + bl2[0];
        float l1 = red1[0] + bl2[1];
        float m = fmaxf(l0, l1);
        float lse = m + logf(expf(l0 - m) + expf(l1 - m));
        out[(long long)g * 2 + 0] = l0 - lse;
        out[(long long)g * 2 + 1] = l1 - lse;
    }
}

// ---------------- launch ----------------

extern "C" void kernel_launch(void* const* d_in, const int* in_sizes, int n_in,
                              void* d_out, int out_size, void* d_ws, size_t ws_size,
                              hipStream_t stream) {
    const float* x    = (const float*)d_in[0];
    const int*   ei   = (const int*)d_in[1];
    const int*   batch= (const int*)d_in[2];
    const float* W1   = (const float*)d_in[3];
    const float* b1   = (const float*)d_in[4];
    const float* W2   = (const float*)d_in[5];
    const float* b2   = (const float*)d_in[6];
    const float* W3   = (const float*)d_in[7];
    const float* b3   = (const float*)d_in[8];
    const float* Wl1  = (const float*)d_in[9];
    const float* bl1  = (const float*)d_in[10];
    const float* Wl2  = (const float*)d_in[11];
    const float* bl2  = (const float*)d_in[12];
    float* out = (float*)d_out;

    const int N = in_sizes[2];
    const long long E = (long long)in_sizes[1] / 2;
    const int G = out_size / 2;
    const int K = (N + RANGE - 1) >> RSHIFT;

    // workspace layout
    char* ws = (char*)d_ws;
    size_t off = 0;
    char*  regionA = ws + off;           off += (size_t)E * 4;       // pairs; later tpA (bf16 N*32)
    char*  bufB    = ws + off;           off += (size_t)N * LAT * 2; // tpB (bf16)
    int*   csr_src = (int*)  (ws + off); off += (size_t)E * 4;
    float* dinv    = (float*)(ws + off); off += (size_t)N * 4;
    int*   rowptr  = (int*)  (ws + off); off += (size_t)(N + 1) * 4;
    int*   pmap    = (int*)  (ws + off); off += (size_t)N * 4;
    int*   idx     = (int*)  (ws + off); off += (size_t)G * 4;
    float* pooled  = (float*)(ws + off); off += (size_t)G * (3 * LAT) * 4;
    int*   bucketTot    = (int*)(ws + off); off += (KMAX + 1) * 4;
    int*   bucketStart  = (int*)(ws + off); off += (KMAX + 1) * 4;
    int*   bucketCursor = (int*)(ws + off); off += KMAX * 4;

    unsigned int* pairs = (unsigned int*)regionA;   // dead before gemm_in writes tpA
    u16* tpA = (u16*)regionA;
    u16* tpB = (u16*)bufB;

    const int BS = 256;
    const int gatherBlocks = (N + 7) / 8;
    const int groBlocks = (G + 7) / 8;
    const int ginBlocks = (N + GIN_ROWS - 1) / GIN_ROWS;
    const int partBlocks = (int)((E + PART_CH - 1) / PART_CH);

    // ---- CSR build via radix partition ----
    hipMemsetAsync(bucketTot, 0, (size_t)(KMAX + 1) * 4, stream);
    pmap_kernel<<<(N + BS - 1) / BS, BS, 0, stream>>>(batch, pmap, N);
    compute_idx_kernel<<<(G + BS - 1) / BS, BS, 0, stream>>>(batch, idx, N, G);
    bucket_hist_kernel<<<512, BS, 0, stream>>>(ei, bucketTot, E, K);
    bucket_scan_kernel<<<1, KMAX, 0, stream>>>(bucketTot, bucketStart, bucketCursor, K, (int)E, rowptr, N);
    partition_kernel<<<partBlocks, BS, 0, stream>>>(ei, bucketCursor, pairs, E, K);
    build_csr_kernel<<<K, RANGE, 0, stream>>>(pairs, bucketStart, rowptr, dinv, csr_src, N);

    // ---- layer 1 transform ----
    gemm_in_kernel<<<ginBlocks, BS, 0, stream>>>(x, W1, dinv, tpA, N);

    // ---- fused layers 1-2 over all N; layer 3 over readout nodes only ----
    gather_fused_kernel<<<gatherBlocks, BS, 0, stream>>>(rowptr, csr_src, tpA, dinv, b1, pmap,
                                                         pooled, 0, W2, tpB, N);
    gather_fused_kernel<<<gatherBlocks, BS, 0, stream>>>(rowptr, csr_src, tpB, dinv, b2, pmap,
                                                         pooled, LAT, W3, tpA, N);
    gather_readout_kernel<<<groBlocks, BS, 0, stream>>>(rowptr, csr_src, tpA, dinv, b3, idx,
                                                        pooled, 2 * LAT, G);

    // ---- MLP head ----
    mlp_head_kernel<<<G, HID, 0, stream>>>(pooled, Wl1, bl1, Wl2, bl2, out, G);
}

// Round 11
// 574.820 us; speedup vs baseline: 1.8811x; 1.1528x over previous
//
#include <hip/hip_runtime.h>
#include <hip/hip_bf16.h>
#include <math.h>

#define IN_DIM 128
#define LAT 32
#define HID 128
#define RSHIFT 8          // nodes per bucket = 256
#define RANGE 256
#define KMAX 1024
#define PART_CH 12288     // LDS-staged counting sort: 48KB stage + 13KB tables
#define GIN_ROWS 32       // rows per block in gemm_in
#define LCAP 128          // worklist cap per graph (max deg+1; Poisson(32) max ~60)

typedef unsigned short u16;

__device__ __forceinline__ float bf2f(u16 v) {
    return __uint_as_float(((unsigned int)v) << 16);
}
__device__ __forceinline__ u16 f2bf(float f) {
    unsigned int u = __float_as_uint(f);
    u += 0x7fff + ((u >> 16) & 1);   // round-to-nearest-even
    return (u16)(u >> 16);
}

// ---------------- setup ----------------

__global__ void pmap_kernel(const int* __restrict__ batch, int* __restrict__ pmap, int N) {
    int v = blockIdx.x * blockDim.x + threadIdx.x;
    if (v >= N) return;
    int b = batch[v];
    int prev = (v == 0) ? -1 : batch[v - 1];
    pmap[v] = (b != prev) ? (b + 1) : 0;
}

__global__ void compute_idx_kernel(const int* __restrict__ batch, int* __restrict__ idx,
                                   int N, int G) {
    int g = blockIdx.x * blockDim.x + threadIdx.x;
    if (g >= G) return;
    int lo = 0, hi = N;
    while (lo < hi) {
        int mid = (lo + hi) >> 1;
        if (batch[mid] < g) lo = mid + 1; else hi = mid;
    }
    idx[g] = lo;
}

// ---------------- radix-partition CSR build ----------------

__global__ void bucket_hist_kernel(const int* __restrict__ ei, int* __restrict__ bucketTot,
                                   long long E, int K) {
    __shared__ int hist[KMAX];
    for (int b = threadIdx.x; b < K; b += blockDim.x) hist[b] = 0;
    __syncthreads();
    long long tid = (long long)blockIdx.x * blockDim.x + threadIdx.x;
    long long stride = (long long)gridDim.x * blockDim.x;
    for (long long e = tid; e < E; e += stride) {
        int d = ei[E + e];
        atomicAdd(&hist[d >> RSHIFT], 1);
    }
    __syncthreads();
    for (int b = threadIdx.x; b < K; b += blockDim.x) {
        int h = hist[b];
        if (h) atomicAdd(&bucketTot[b], h);
    }
}

__global__ void bucket_scan_kernel(const int* __restrict__ bucketTot, int* __restrict__ bucketStart,
                                   int* __restrict__ bucketCursor, int K, int Etot,
                                   int* __restrict__ rowptr, int N) {
    __shared__ int s[KMAX];
    int t = threadIdx.x;
    int v = (t < K) ? bucketTot[t] : 0;
    s[t] = v;
    __syncthreads();
    for (int off = 1; off < KMAX; off <<= 1) {
        int tmp = (t >= off) ? s[t - off] : 0;
        __syncthreads();
        s[t] += tmp;
        __syncthreads();
    }
    if (t < K) {
        int excl = s[t] - v;
        bucketStart[t] = excl;
        bucketCursor[t] = excl;
    }
    if (t == 0) {
        bucketStart[K] = Etot;
        rowptr[N] = Etot;
    }
}

// Block-local LDS counting sort, then contiguous per-bucket run flushes.
__global__ void partition_kernel(const int* __restrict__ ei, int* __restrict__ bucketCursor,
                                 unsigned int* __restrict__ pairs, long long E, int K) {
    __shared__ unsigned int stage[PART_CH];   // 48KB
    __shared__ int histS[KMAX];               // counts -> exclusive local offsets
    __shared__ int curS[KMAX];
    __shared__ int gbase[KMAX];
    __shared__ int tsum[256];
    int t = threadIdx.x;
    for (int b = t; b < KMAX; b += 256) histS[b] = 0;
    __syncthreads();
    long long e0 = (long long)blockIdx.x * PART_CH;
    int cnt = (int)min((long long)PART_CH, E - e0);
    for (int i = t; i < cnt; i += 256) {
        int d = ei[E + e0 + i];
        atomicAdd(&histS[d >> RSHIFT], 1);
    }
    __syncthreads();
    for (int b = t; b < K; b += 256) {
        int h = histS[b];
        gbase[b] = h ? atomicAdd(&bucketCursor[b], h) : 0;
    }
    int h0 = histS[4 * t + 0], h1 = histS[4 * t + 1],
        h2 = histS[4 * t + 2], h3 = histS[4 * t + 3];
    int sum = h0 + h1 + h2 + h3;
    tsum[t] = sum;
    __syncthreads();
    for (int off = 1; off < 256; off <<= 1) {
        int v = (t >= off) ? tsum[t - off] : 0;
        __syncthreads();
        tsum[t] += v;
        __syncthreads();
    }
    int base = tsum[t] - sum;
    histS[4 * t + 0] = base;
    histS[4 * t + 1] = base + h0;
    histS[4 * t + 2] = base + h0 + h1;
    histS[4 * t + 3] = base + h0 + h1 + h2;
    curS[4 * t + 0] = base;
    curS[4 * t + 1] = base + h0;
    curS[4 * t + 2] = base + h0 + h1;
    curS[4 * t + 3] = base + h0 + h1 + h2;
    __syncthreads();
    for (int i = t; i < cnt; i += 256) {
        long long e = e0 + i;
        unsigned int s = (unsigned int)ei[e];
        int d = ei[E + e];
        int b = d >> RSHIFT;
        int p = atomicAdd(&curS[b], 1);
        stage[p] = (s << RSHIFT) | (unsigned int)(d & (RANGE - 1));
    }
    __syncthreads();
    for (int i = t; i < cnt; i += 256) {
        int lo = 0, hi = K - 1;
        while (lo < hi) {                      // last b with lofs[b] <= i
            int mid = (lo + hi + 1) >> 1;
            if (histS[mid] <= i) lo = mid; else hi = mid - 1;
        }
        pairs[(long long)gbase[lo] + (i - histS[lo])] = stage[i];
    }
}

__global__ void build_csr_kernel(const unsigned int* __restrict__ pairs,
                                 const int* __restrict__ bucketStart,
                                 int* __restrict__ rowptr, float* __restrict__ dinv,
                                 int* __restrict__ csr_src, int N) {
    __shared__ int hist[RANGE];
    __shared__ int scanb[RANGE];
    __shared__ int cursor[RANGE];
    int b = blockIdx.x;
    int t = threadIdx.x;
    int base = b << RSHIFT;
    int s0 = bucketStart[b];
    int s1 = bucketStart[b + 1];
    int cnt = s1 - s0;
    hist[t] = 0;
    __syncthreads();
    for (int i = t; i < cnt; i += RANGE) {
        unsigned int p = pairs[s0 + i];
        atomicAdd(&hist[p & (RANGE - 1)], 1);
    }
    __syncthreads();
    int deg = hist[t];
    scanb[t] = deg;
    __syncthreads();
    for (int off = 1; off < RANGE; off <<= 1) {
        int tmp = (t >= off) ? scanb[t - off] : 0;
        __syncthreads();
        scanb[t] += tmp;
        __syncthreads();
    }
    int excl = scanb[t] - deg;
    int node = base + t;
    if (node < N) {
        rowptr[node] = s0 + excl;
        dinv[node] = rsqrtf((float)(deg + 1));   // +1 self-loop
    }
    cursor[t] = s0 + excl;
    __syncthreads();
    for (int i = t; i < cnt; i += RANGE) {
        unsigned int p = pairs[s0 + i];
        int slot = atomicAdd(&cursor[p & (RANGE - 1)], 1);
        csr_src[slot] = (int)(p >> RSHIFT);
    }
}

// ---------------- layer-2 worklist: readout nodes + their in-neighbors ----------------

__global__ void rscan_kernel(const int* __restrict__ rowptr, const int* __restrict__ idx,
                             int* __restrict__ offs, int* __restrict__ totalT, int G) {
    __shared__ int s[256];
    int t = threadIdx.x;
    int per = (G + 255) / 256;   // <=16 assumed
    int loc[16];
    int base = t * per;
    int sum = 0;
    for (int k = 0; k < per; k++) {
        int g = base + k;
        int c = 0;
        if (g < G) { int v = idx[g]; c = rowptr[v + 1] - rowptr[v] + 1; }
        loc[k] = sum; sum += c;
    }
    s[t] = sum;
    __syncthreads();
    for (int off = 1; off < 256; off <<= 1) {
        int v = (t >= off) ? s[t - off] : 0;
        __syncthreads();
        s[t] += v;
        __syncthreads();
    }
    int b0 = (t > 0) ? s[t - 1] : 0;
    for (int k = 0; k < per; k++) {
        int g = base + k;
        if (g < G) offs[g] = b0 + loc[k];
    }
    if (t == 255) totalT[0] = s[255];
}

__global__ void rfill_kernel(const int* __restrict__ rowptr, const int* __restrict__ csr_src,
                             const int* __restrict__ idx, const int* __restrict__ offs,
                             int* __restrict__ list, int G) {
    int g = blockIdx.x * 4 + (int)(threadIdx.x >> 6);
    int lane = threadIdx.x & 63;
    if (g >= G) return;
    int v = idx[g];
    int o = offs[g];
    int s0 = rowptr[v], s1 = rowptr[v + 1];
    if (lane == 0) list[o] = v;
    for (int i = lane; i < s1 - s0; i += 64) list[o + 1 + i] = csr_src[s0 + i];
}

// ---------------- input transform: tp1 = (x@W1)*dinv, bf16 row-major ----------------

__global__ void gemm_in_kernel(const float* __restrict__ x, const float* __restrict__ W,
                               const float* __restrict__ dinv, u16* __restrict__ tp, int N) {
    __shared__ float Wl[IN_DIM * LAT];         // 16 KB
    __shared__ float Xl[GIN_ROWS * IN_DIM];    // 16 KB
    int t = threadIdx.x;
    for (int i = t; i < IN_DIM * LAT; i += 256) Wl[i] = W[i];
    long long rowBase = (long long)blockIdx.x * GIN_ROWS;
    int nrow = min(GIN_ROWS, (int)(N - rowBase));
    {
        const float4* x4 = reinterpret_cast<const float4*>(x + rowBase * IN_DIM);
        float4* X4 = reinterpret_cast<float4*>(Xl);
        int nf4 = nrow * (IN_DIM / 4);
        for (int i = t; i < nf4; i += 256) X4[i] = x4[i];   // coalesced
    }
    __syncthreads();
    int g = t >> 5;            // col-group 0..7
    int c = t & 31;
    int r0 = g * 4;            // 4 local rows per group
    float acc0 = 0.f, acc1 = 0.f, acc2 = 0.f, acc3 = 0.f;
#pragma unroll 4
    for (int k = 0; k < IN_DIM; k += 4) {
        float w0 = Wl[(k + 0) * LAT + c];
        float w1 = Wl[(k + 1) * LAT + c];
        float w2 = Wl[(k + 2) * LAT + c];
        float w3 = Wl[(k + 3) * LAT + c];
        float4 xa = *reinterpret_cast<const float4*>(&Xl[(r0 + 0) * IN_DIM + k]);
        float4 xb = *reinterpret_cast<const float4*>(&Xl[(r0 + 1) * IN_DIM + k]);
        float4 xc = *reinterpret_cast<const float4*>(&Xl[(r0 + 2) * IN_DIM + k]);
        float4 xd = *reinterpret_cast<const float4*>(&Xl[(r0 + 3) * IN_DIM + k]);
        acc0 += xa.x * w0 + xa.y * w1 + xa.z * w2 + xa.w * w3;
        acc1 += xb.x * w0 + xb.y * w1 + xb.z * w2 + xb.w * w3;
        acc2 += xc.x * w0 + xc.y * w1 + xc.z * w2 + xc.w * w3;
        acc3 += xd.x * w0 + xd.y * w1 + xd.z * w2 + xd.w * w3;
    }
    long long rr = rowBase + r0;
    if (r0 + 0 < nrow) tp[(rr + 0) * LAT + c] = f2bf(acc0 * dinv[rr + 0]);
    if (r0 + 1 < nrow) tp[(rr + 1) * LAT + c] = f2bf(acc1 * dinv[rr + 1]);
    if (r0 + 2 < nrow) tp[(rr + 2) * LAT + c] = f2bf(acc2 * dinv[rr + 2]);
    if (r0 + 3 < nrow) tp[(rr + 3) * LAT + c] = f2bf(acc3 * dinv[rr + 3]);
}

// ---------------- fused gather + tanh + next-layer GEMM ----------------
// vmap/nvDev: optional node worklist (layer 2 runs only on readout+neighbors).

__global__ void gather_fused_kernel(const int* __restrict__ rowptr, const int* __restrict__ csr_src,
                                    const u16* __restrict__ tp, const float* __restrict__ dinv,
                                    const float* __restrict__ bcur, const int* __restrict__ pmap,
                                    float* __restrict__ pooled, int colOff,
                                    const float* __restrict__ Wnext, u16* __restrict__ tpNext,
                                    const int* __restrict__ vmap, const int* __restrict__ nvDev,
                                    int nvMax) {
    __shared__ float Wl[LAT * LAT];
    for (int i = threadIdx.x; i < LAT * LAT; i += blockDim.x) Wl[i] = Wnext[i];
    __syncthreads();
    int vi = blockIdx.x * 8 + (int)(threadIdx.x >> 5);
    int f = threadIdx.x & 31;
    int Nv = nvDev ? nvDev[0] : nvMax;
    if (vi >= Nv) return;
    int v = vmap ? vmap[vi] : vi;
    int start = rowptr[v];
    int end = rowptr[v + 1];
    float acc = bf2f(tp[(long long)v * LAT + f]);   // self-loop term
    int e = start;
    for (; e + 32 <= end; e += 32) {
        int s = csr_src[e + f];                     // coalesced index load
#pragma unroll
        for (int jj = 0; jj < 32; jj += 8) {
            int s0 = __shfl(s, jj + 0, 32), s1 = __shfl(s, jj + 1, 32);
            int s2 = __shfl(s, jj + 2, 32), s3 = __shfl(s, jj + 3, 32);
            int s4 = __shfl(s, jj + 4, 32), s5 = __shfl(s, jj + 5, 32);
            int s6 = __shfl(s, jj + 6, 32), s7 = __shfl(s, jj + 7, 32);
            float r0 = bf2f(tp[(long long)s0 * LAT + f]);
            float r1 = bf2f(tp[(long long)s1 * LAT + f]);
            float r2 = bf2f(tp[(long long)s2 * LAT + f]);
            float r3 = bf2f(tp[(long long)s3 * LAT + f]);
            float r4 = bf2f(tp[(long long)s4 * LAT + f]);
            float r5 = bf2f(tp[(long long)s5 * LAT + f]);
            float r6 = bf2f(tp[(long long)s6 * LAT + f]);
            float r7 = bf2f(tp[(long long)s7 * LAT + f]);
            acc += ((r0 + r1) + (r2 + r3)) + ((r4 + r5) + (r6 + r7));
        }
    }
    int rem = end - e;
    if (rem > 0) {
        int s = (f < rem) ? csr_src[e + f] : 0;
        int j = 0;
        for (; j + 4 <= rem; j += 4) {
            int s0 = __shfl(s, j + 0, 32), s1 = __shfl(s, j + 1, 32);
            int s2 = __shfl(s, j + 2, 32), s3 = __shfl(s, j + 3, 32);
            float r0 = bf2f(tp[(long long)s0 * LAT + f]);
            float r1 = bf2f(tp[(long long)s1 * LAT + f]);
            float r2 = bf2f(tp[(long long)s2 * LAT + f]);
            float r3 = bf2f(tp[(long long)s3 * LAT + f]);
            acc += (r0 + r1) + (r2 + r3);
        }
        for (; j < rem; j++) {
            int sj = __shfl(s, j, 32);
            acc += bf2f(tp[(long long)sj * LAT + f]);
        }
    }
    float dv = dinv[v];
    float hv = tanhf(dv * acc + bcur[f]);
    int pg = pmap[v];
    if (pg) pooled[(long long)(pg - 1) * (3 * LAT) + colOff + f] = hv;
    float acc2 = 0.f;
#pragma unroll
    for (int k = 0; k < LAT; k++) acc2 += __shfl(hv, k, 32) * Wl[k * LAT + f];
    tpNext[(long long)v * LAT + f] = f2bf(acc2 * dv);
}

// ---------------- layer-3 gather: only the G readout nodes ----------------

__global__ void gather_readout_kernel(const int* __restrict__ rowptr, const int* __restrict__ csr_src,
                                      const u16* __restrict__ tp, const float* __restrict__ dinv,
                                      const float* __restrict__ bcur, const int* __restrict__ idx,
                                      float* __restrict__ pooled, int colOff, int G) {
    int vi = blockIdx.x * 8 + (int)(threadIdx.x >> 5);
    int f = threadIdx.x & 31;
    if (vi >= G) return;
    int v = idx[vi];
    int start = rowptr[v];
    int end = rowptr[v + 1];
    float acc = bf2f(tp[(long long)v * LAT + f]);
    int e = start;
    for (; e + 32 <= end; e += 32) {
        int s = csr_src[e + f];
#pragma unroll
        for (int jj = 0; jj < 32; jj += 8) {
            int s0 = __shfl(s, jj + 0, 32), s1 = __shfl(s, jj + 1, 32);
            int s2 = __shfl(s, jj + 2, 32), s3 = __shfl(s, jj + 3, 32);
            int s4 = __shfl(s, jj + 4, 32), s5 = __shfl(s, jj + 5, 32);
            int s6 = __shfl(s, jj + 6, 32), s7 = __shfl(s, jj + 7, 32);
            float r0 = bf2f(tp[(long long)s0 * LAT + f]);
            float r1 = bf2f(tp[(long long)s1 * LAT + f]);
            float r2 = bf2f(tp[(long long)s2 * LAT + f]);
            float r3 = bf2f(tp[(long long)s3 * LAT + f]);
            float r4 = bf2f(tp[(long long)s4 * LAT + f]);
            float r5 = bf2f(tp[(long long)s5 * LAT + f]);
            float r6 = bf2f(tp[(long long)s6 * LAT + f]);
            float r7 = bf2f(tp[(long long)s7 * LAT + f]);
            acc += ((r0 + r1) + (r2 + r3)) + ((r4 + r5) + (r6 + r7));
        }
    }
    int rem = end - e;
    if (rem > 0) {
        int s = (f < rem) ? csr_src[e + f] : 0;
        for (int j = 0; j < rem; j++) {
            int sj = __shfl(s, j, 32);
            acc += bf2f(tp[(long long)sj * LAT + f]);
        }
    }
    float hv = tanhf(dinv[v] * acc + bcur[f]);
    pooled[(long long)vi * (3 * LAT) + colOff + f] = hv;
}

// ---------------- MLP head ----------------

__global__ void mlp_head_kernel(const float* __restrict__ pooled,
                                const float* __restrict__ Wl1, const float* __restrict__ bl1,
                                const float* __restrict__ Wl2, const float* __restrict__ bl2,
                                float* __restrict__ out, int G) {
    __shared__ float prow[3 * LAT];
    __shared__ float red0[HID];
    __shared__ float red1[HID];
    int g = blockIdx.x;
    int j = threadIdx.x;
    if (j < 3 * LAT) prow[j] = pooled[(long long)g * (3 * LAT) + j];
    __syncthreads();
    float acc = bl1[j];
#pragma unroll 8
    for (int k = 0; k < 3 * LAT; k++) acc += prow[k] * Wl1[k * HID + j];
    float hj = fmaxf(acc, 0.f);
    red0[j] = hj * Wl2[j * 2 + 0];
    red1[j] = hj * Wl2[j * 2 + 1];
    __syncthreads();
    for (int s = HID / 2; s > 0; s >>= 1) {
        if (j < s) { red0[j] += red0[j + s]; red1[j] += red1[j + s]; }
        __syncthreads();
    }
    if (j == 0) {
        float l0 = red0[0] + bl2[0];
        float l1 = red1[0] + bl2[1];
        float m = fmaxf(l0, l1);
        float lse = m + logf(expf(l0 - m) + expf(l1 - m));
        out[(long long)g * 2 + 0] = l0 - lse;
        out[(long long)g * 2 + 1] = l1 - lse;
    }
}

// ---------------- launch ----------------

extern "C" void kernel_launch(void* const* d_in, const int* in_sizes, int n_in,
                              void* d_out, int out_size, void* d_ws, size_t ws_size,
                              hipStream_t stream) {
    const float* x    = (const float*)d_in[0];
    const int*   ei   = (const int*)d_in[1];
    const int*   batch= (const int*)d_in[2];
    const float* W1   = (const float*)d_in[3];
    const float* b1   = (const float*)d_in[4];
    const float* W2   = (const float*)d_in[5];
    const float* b2   = (const float*)d_in[6];
    const float* W3   = (const float*)d_in[7];
    const float* b3   = (const float*)d_in[8];
    const float* Wl1  = (const float*)d_in[9];
    const float* bl1  = (const float*)d_in[10];
    const float* Wl2  = (const float*)d_in[11];
    const float* bl2  = (const float*)d_in[12];
    float* out = (float*)d_out;

    const int N = in_sizes[2];
    const long long E = (long long)in_sizes[1] / 2;
    const int G = out_size / 2;
    const int K = (N + RANGE - 1) >> RSHIFT;
    const int capT = G * LCAP;

    // workspace layout
    char* ws = (char*)d_ws;
    size_t off = 0;
    char*  regionA = ws + off;           off += (size_t)E * 4;       // pairs; later tpA (bf16 N*32)
    char*  bufB    = ws + off;           off += (size_t)N * LAT * 2; // tpB (bf16)
    int*   csr_src = (int*)  (ws + off); off += (size_t)E * 4;
    float* dinv    = (float*)(ws + off); off += (size_t)N * 4;
    int*   rowptr  = (int*)  (ws + off); off += (size_t)(N + 1) * 4;
    int*   pmap    = (int*)  (ws + off); off += (size_t)N * 4;
    int*   idx     = (int*)  (ws + off); off += (size_t)G * 4;
    float* pooled  = (float*)(ws + off); off += (size_t)G * (3 * LAT) * 4;
    int*   bucketTot    = (int*)(ws + off); off += (KMAX + 1) * 4;
    int*   bucketStart  = (int*)(ws + off); off += (KMAX + 1) * 4;
    int*   bucketCursor = (int*)(ws + off); off += KMAX * 4;
    int*   offs    = (int*)  (ws + off); off += (size_t)G * 4;
    int*   totalT  = (int*)  (ws + off); off += 4;
    int*   list    = (int*)  (ws + off); off += (size_t)capT * 4;

    unsigned int* pairs = (unsigned int*)regionA;   // dead before gemm_in writes tpA
    u16* tpA = (u16*)regionA;
    u16* tpB = (u16*)bufB;

    const int BS = 256;
    const int gatherBlocks = (N + 7) / 8;
    const int g2Blocks = (capT + 7) / 8;     // early-exit via totalT device count
    const int groBlocks = (G + 7) / 8;
    const int ginBlocks = (N + GIN_ROWS - 1) / GIN_ROWS;
    const int partBlocks = (int)((E + PART_CH - 1) / PART_CH);

    // ---- CSR build via radix partition ----
    hipMemsetAsync(bucketTot, 0, (size_t)(KMAX + 1) * 4, stream);
    pmap_kernel<<<(N + BS - 1) / BS, BS, 0, stream>>>(batch, pmap, N);
    compute_idx_kernel<<<(G + BS - 1) / BS, BS, 0, stream>>>(batch, idx, N, G);
    bucket_hist_kernel<<<512, BS, 0, stream>>>(ei, bucketTot, E, K);
    bucket_scan_kernel<<<1, KMAX, 0, stream>>>(bucketTot, bucketStart, bucketCursor, K, (int)E, rowptr, N);
    partition_kernel<<<partBlocks, BS, 0, stream>>>(ei, bucketCursor, pairs, E, K);
    build_csr_kernel<<<K, RANGE, 0, stream>>>(pairs, bucketStart, rowptr, dinv, csr_src, N);

    // ---- layer-2 worklist (readout nodes + in-neighbors) ----
    rscan_kernel<<<1, 256, 0, stream>>>(rowptr, idx, offs, totalT, G);
    rfill_kernel<<<(G + 3) / 4, BS, 0, stream>>>(rowptr, csr_src, idx, offs, list, G);

    // ---- layer 1 transform ----
    gemm_in_kernel<<<ginBlocks, BS, 0, stream>>>(x, W1, dinv, tpA, N);

    // ---- layer 1 over all N; layer 2 over worklist; layer 3 over readout ----
    gather_fused_kernel<<<gatherBlocks, BS, 0, stream>>>(rowptr, csr_src, tpA, dinv, b1, pmap,
                                                         pooled, 0, W2, tpB,
                                                         (const int*)nullptr, (const int*)nullptr, N);
    gather_fused_kernel<<<g2Blocks, BS, 0, stream>>>(rowptr, csr_src, tpB, dinv, b2, pmap,
                                                     pooled, LAT, W3, tpA,
                                                     list, totalT, capT);
    gather_readout_kernel<<<groBlocks, BS, 0, stream>>>(rowptr, csr_src, tpA, dinv, b3, idx,
                                                        pooled, 2 * LAT, G);

    // ---- MLP head ----
    mlp_head_kernel<<<G, HID, 0, stream>>>(pooled, Wl1, bl1, Wl2, bl2, out, G);
}

// Round 12
// 463.108 us; speedup vs baseline: 2.3348x; 1.2412x over previous
//
#include <hip/hip_runtime.h>
#include <hip/hip_bf16.h>
#include <math.h>

#define IN_DIM 128
#define LAT 32
#define HID 128
#define RSHIFT 8          // nodes per bucket = 256
#define RANGE 256
#define KMAX 1024
#define PART_CH 12288     // LDS-staged counting sort chunk
#define PART_T 1024       // partition block threads (round-11: 256 -> 1024, 4x waves/CU)
#define CAP 9216          // padded bucket capacity (mean 8184, +11 sigma)
#define GIN_ROWS 32       // rows per block in gemm_in
#define LCAP 128          // worklist cap per graph (max deg+1)

typedef unsigned short u16;

__device__ __forceinline__ float bf2f(u16 v) {
    return __uint_as_float(((unsigned int)v) << 16);
}
__device__ __forceinline__ u16 f2bf(float f) {
    unsigned int u = __float_as_uint(f);
    u += 0x7fff + ((u >> 16) & 1);   // round-to-nearest-even
    return (u16)(u >> 16);
}

// ---------------- setup ----------------

__global__ void pmap_kernel(const int* __restrict__ batch, int* __restrict__ pmap, int N) {
    int v = blockIdx.x * blockDim.x + threadIdx.x;
    if (v >= N) return;
    int b = batch[v];
    int prev = (v == 0) ? -1 : batch[v - 1];
    pmap[v] = (b != prev) ? (b + 1) : 0;
}

__global__ void compute_idx_kernel(const int* __restrict__ batch, int* __restrict__ idx,
                                   int N, int G) {
    int g = blockIdx.x * blockDim.x + threadIdx.x;
    if (g >= G) return;
    int lo = 0, hi = N;
    while (lo < hi) {
        int mid = (lo + hi) >> 1;
        if (batch[mid] < g) lo = mid + 1; else hi = mid;
    }
    idx[g] = lo;
}

__global__ void init_cursor_kernel(int* __restrict__ bucketCursor, int K) {
    int b = blockIdx.x * blockDim.x + threadIdx.x;
    if (b < K) bucketCursor[b] = b * CAP;
}

// ---------------- radix-partition CSR build (no pre-hist: padded regions) ----------------

__global__ void partition_kernel(const int* __restrict__ ei, int* __restrict__ bucketCursor,
                                 unsigned int* __restrict__ pairs, long long E, int K) {
    __shared__ unsigned int stage[PART_CH];   // 48KB
    __shared__ int histS[KMAX];               // counts -> local exclusive offsets
    __shared__ int curS[KMAX];
    __shared__ int gbase[KMAX];               // absolute padded dest start
    __shared__ int ssum[PART_T];
    int t = threadIdx.x;
    if (t < KMAX) histS[t] = 0;
    __syncthreads();
    long long e0 = (long long)blockIdx.x * PART_CH;
    int cnt = (int)min((long long)PART_CH, E - e0);
    for (int i = t; i < cnt; i += PART_T) {
        int d = ei[E + e0 + i];
        atomicAdd(&histS[d >> RSHIFT], 1);
    }
    __syncthreads();
    int h = (t < K) ? histS[t] : 0;
    if (t < K) gbase[t] = h ? atomicAdd(&bucketCursor[t], h) : 0;
    ssum[t] = h;
    __syncthreads();
    for (int off = 1; off < PART_T; off <<= 1) {
        int v = (t >= off) ? ssum[t - off] : 0;
        __syncthreads();
        ssum[t] += v;
        __syncthreads();
    }
    int excl = ssum[t] - h;
    if (t < KMAX) { histS[t] = excl; curS[t] = excl; }
    __syncthreads();
    // scatter into LDS stage (sorted by bucket)
    for (int i = t; i < cnt; i += PART_T) {
        long long e = e0 + i;
        unsigned int s = (unsigned int)ei[e];
        int d = ei[E + e];
        int b = d >> RSHIFT;
        int p = atomicAdd(&curS[b], 1);
        stage[p] = (s << RSHIFT) | (unsigned int)(d & (RANGE - 1));
    }
    __syncthreads();
    // flush: contiguous positions -> coalesced runs into padded bucket regions
    for (int i = t; i < cnt; i += PART_T) {
        int lo = 0, hi = K - 1;
        while (lo < hi) {                      // last b with histS[b] <= i
            int mid = (lo + hi + 1) >> 1;
            if (histS[mid] <= i) lo = mid; else hi = mid - 1;
        }
        pairs[(long long)gbase[lo] + (i - histS[lo])] = stage[i];
    }
}

// single-block scan of per-bucket counts -> compacted bucketStart + rowptr[N]
__global__ void post_scan_kernel(const int* __restrict__ bucketCursor, int* __restrict__ bucketStart,
                                 int K, int Etot, int* __restrict__ rowptr, int N) {
    __shared__ int s[KMAX];
    int t = threadIdx.x;
    int c = (t < K) ? (bucketCursor[t] - t * CAP) : 0;
    s[t] = c;
    __syncthreads();
    for (int off = 1; off < KMAX; off <<= 1) {
        int v = (t >= off) ? s[t - off] : 0;
        __syncthreads();
        s[t] += v;
        __syncthreads();
    }
    if (t < K) bucketStart[t] = s[t] - c;
    if (t == 0) {
        bucketStart[K] = Etot;
        rowptr[N] = Etot;
    }
}

__global__ void build_csr_kernel(const unsigned int* __restrict__ pairs,
                                 const int* __restrict__ bucketStart,
                                 int* __restrict__ rowptr, float* __restrict__ dinv,
                                 int* __restrict__ csr_src, int N) {
    __shared__ int hist[RANGE];
    __shared__ int scanb[RANGE];
    __shared__ int cursor[RANGE];
    int b = blockIdx.x;
    int t = threadIdx.x;
    int base = b << RSHIFT;
    int s0 = bucketStart[b];
    int cnt = bucketStart[b + 1] - s0;
    long long rbase = (long long)b * CAP;   // padded read region
    hist[t] = 0;
    __syncthreads();
    for (int i = t; i < cnt; i += RANGE) {
        unsigned int p = pairs[rbase + i];
        atomicAdd(&hist[p & (RANGE - 1)], 1);
    }
    __syncthreads();
    int deg = hist[t];
    scanb[t] = deg;
    __syncthreads();
    for (int off = 1; off < RANGE; off <<= 1) {
        int tmp = (t >= off) ? scanb[t - off] : 0;
        __syncthreads();
        scanb[t] += tmp;
        __syncthreads();
    }
    int excl = scanb[t] - deg;
    int node = base + t;
    if (node < N) {
        rowptr[node] = s0 + excl;
        dinv[node] = rsqrtf((float)(deg + 1));   // +1 self-loop
    }
    cursor[t] = s0 + excl;
    __syncthreads();
    for (int i = t; i < cnt; i += RANGE) {
        unsigned int p = pairs[rbase + i];
        int slot = atomicAdd(&cursor[p & (RANGE - 1)], 1);
        csr_src[slot] = (int)(p >> RSHIFT);
    }
}

// ---------------- layer-2 worklist: readout nodes + their in-neighbors ----------------

__global__ void rscan_kernel(const int* __restrict__ rowptr, const int* __restrict__ idx,
                             int* __restrict__ offs, int* __restrict__ totalT, int G) {
    __shared__ int s[256];
    int t = threadIdx.x;
    int per = (G + 255) / 256;   // <=16 assumed
    int loc[16];
    int base = t * per;
    int sum = 0;
    for (int k = 0; k < per; k++) {
        int g = base + k;
        int c = 0;
        if (g < G) { int v = idx[g]; c = rowptr[v + 1] - rowptr[v] + 1; }
        loc[k] = sum; sum += c;
    }
    s[t] = sum;
    __syncthreads();
    for (int off = 1; off < 256; off <<= 1) {
        int v = (t >= off) ? s[t - off] : 0;
        __syncthreads();
        s[t] += v;
        __syncthreads();
    }
    int b0 = (t > 0) ? s[t - 1] : 0;
    for (int k = 0; k < per; k++) {
        int g = base + k;
        if (g < G) offs[g] = b0 + loc[k];
    }
    if (t == 255) totalT[0] = s[255];
}

__global__ void rfill_kernel(const int* __restrict__ rowptr, const int* __restrict__ csr_src,
                             const int* __restrict__ idx, const int* __restrict__ offs,
                             int* __restrict__ list, int G) {
    int g = blockIdx.x * 4 + (int)(threadIdx.x >> 6);
    int lane = threadIdx.x & 63;
    if (g >= G) return;
    int v = idx[g];
    int o = offs[g];
    int s0 = rowptr[v], s1 = rowptr[v + 1];
    if (lane == 0) list[o] = v;
    for (int i = lane; i < s1 - s0; i += 64) list[o + 1 + i] = csr_src[s0 + i];
}

// ---------------- input transform: tp1 = (x@W1)*dinv, bf16 row-major ----------------

__global__ void gemm_in_kernel(const float* __restrict__ x, const float* __restrict__ W,
                               const float* __restrict__ dinv, u16* __restrict__ tp, int N) {
    __shared__ float Wl[IN_DIM * LAT];         // 16 KB
    __shared__ float Xl[GIN_ROWS * IN_DIM];    // 16 KB
    int t = threadIdx.x;
    for (int i = t; i < IN_DIM * LAT; i += 256) Wl[i] = W[i];
    long long rowBase = (long long)blockIdx.x * GIN_ROWS;
    int nrow = min(GIN_ROWS, (int)(N - rowBase));
    {
        const float4* x4 = reinterpret_cast<const float4*>(x + rowBase * IN_DIM);
        float4* X4 = reinterpret_cast<float4*>(Xl);
        int nf4 = nrow * (IN_DIM / 4);
        for (int i = t; i < nf4; i += 256) X4[i] = x4[i];   // coalesced
    }
    __syncthreads();
    int g = t >> 5;            // col-group 0..7
    int c = t & 31;
    int r0 = g * 4;            // 4 local rows per group
    float acc0 = 0.f, acc1 = 0.f, acc2 = 0.f, acc3 = 0.f;
#pragma unroll 4
    for (int k = 0; k < IN_DIM; k += 4) {
        float w0 = Wl[(k + 0) * LAT + c];
        float w1 = Wl[(k + 1) * LAT + c];
        float w2 = Wl[(k + 2) * LAT + c];
        float w3 = Wl[(k + 3) * LAT + c];
        float4 xa = *reinterpret_cast<const float4*>(&Xl[(r0 + 0) * IN_DIM + k]);
        float4 xb = *reinterpret_cast<const float4*>(&Xl[(r0 + 1) * IN_DIM + k]);
        float4 xc = *reinterpret_cast<const float4*>(&Xl[(r0 + 2) * IN_DIM + k]);
        float4 xd = *reinterpret_cast<const float4*>(&Xl[(r0 + 3) * IN_DIM + k]);
        acc0 += xa.x * w0 + xa.y * w1 + xa.z * w2 + xa.w * w3;
        acc1 += xb.x * w0 + xb.y * w1 + xb.z * w2 + xb.w * w3;
        acc2 += xc.x * w0 + xc.y * w1 + xc.z * w2 + xc.w * w3;
        acc3 += xd.x * w0 + xd.y * w1 + xd.z * w2 + xd.w * w3;
    }
    long long rr = rowBase + r0;
    if (r0 + 0 < nrow) tp[(rr + 0) * LAT + c] = f2bf(acc0 * dinv[rr + 0]);
    if (r0 + 1 < nrow) tp[(rr + 1) * LAT + c] = f2bf(acc1 * dinv[rr + 1]);
    if (r0 + 2 < nrow) tp[(rr + 2) * LAT + c] = f2bf(acc2 * dinv[rr + 2]);
    if (r0 + 3 < nrow) tp[(rr + 3) * LAT + c] = f2bf(acc3 * dinv[rr + 3]);
}

// ---------------- fused gather + tanh + next-layer GEMM ----------------
// vmap/nvDev: optional node worklist (layer 2 runs only on readout+neighbors).

__global__ void gather_fused_kernel(const int* __restrict__ rowptr, const int* __restrict__ csr_src,
                                    const u16* __restrict__ tp, const float* __restrict__ dinv,
                                    const float* __restrict__ bcur, const int* __restrict__ pmap,
                                    float* __restrict__ pooled, int colOff,
                                    const float* __restrict__ Wnext, u16* __restrict__ tpNext,
                                    const int* __restrict__ vmap, const int* __restrict__ nvDev,
                                    int nvMax) {
    __shared__ float Wl[LAT * LAT];
    for (int i = threadIdx.x; i < LAT * LAT; i += blockDim.x) Wl[i] = Wnext[i];
    __syncthreads();
    int vi = blockIdx.x * 8 + (int)(threadIdx.x >> 5);
    int f = threadIdx.x & 31;
    int Nv = nvDev ? nvDev[0] : nvMax;
    if (vi >= Nv) return;
    int v = vmap ? vmap[vi] : vi;
    int start = rowptr[v];
    int end = rowptr[v + 1];
    float acc = bf2f(tp[(long long)v * LAT + f]);   // self-loop term
    int e = start;
    for (; e + 32 <= end; e += 32) {
        int s = csr_src[e + f];                     // coalesced index load
#pragma unroll
        for (int jj = 0; jj < 32; jj += 8) {
            int s0 = __shfl(s, jj + 0, 32), s1 = __shfl(s, jj + 1, 32);
            int s2 = __shfl(s, jj + 2, 32), s3 = __shfl(s, jj + 3, 32);
            int s4 = __shfl(s, jj + 4, 32), s5 = __shfl(s, jj + 5, 32);
            int s6 = __shfl(s, jj + 6, 32), s7 = __shfl(s, jj + 7, 32);
            float r0 = bf2f(tp[(long long)s0 * LAT + f]);
            float r1 = bf2f(tp[(long long)s1 * LAT + f]);
            float r2 = bf2f(tp[(long long)s2 * LAT + f]);
            float r3 = bf2f(tp[(long long)s3 * LAT + f]);
            float r4 = bf2f(tp[(long long)s4 * LAT + f]);
            float r5 = bf2f(tp[(long long)s5 * LAT + f]);
            float r6 = bf2f(tp[(long long)s6 * LAT + f]);
            float r7 = bf2f(tp[(long long)s7 * LAT + f]);
            acc += ((r0 + r1) + (r2 + r3)) + ((r4 + r5) + (r6 + r7));
        }
    }
    int rem = end - e;
    if (rem > 0) {
        int s = (f < rem) ? csr_src[e + f] : 0;
        int j = 0;
        for (; j + 4 <= rem; j += 4) {
            int s0 = __shfl(s, j + 0, 32), s1 = __shfl(s, j + 1, 32);
            int s2 = __shfl(s, j + 2, 32), s3 = __shfl(s, j + 3, 32);
            float r0 = bf2f(tp[(long long)s0 * LAT + f]);
            float r1 = bf2f(tp[(long long)s1 * LAT + f]);
            float r2 = bf2f(tp[(long long)s2 * LAT + f]);
            float r3 = bf2f(tp[(long long)s3 * LAT + f]);
            acc += (r0 + r1) + (r2 + r3);
        }
        for (; j < rem; j++) {
            int sj = __shfl(s, j, 32);
            acc += bf2f(tp[(long long)sj * LAT + f]);
        }
    }
    float dv = dinv[v];
    float hv = tanhf(dv * acc + bcur[f]);
    int pg = pmap[v];
    if (pg) pooled[(long long)(pg - 1) * (3 * LAT) + colOff + f] = hv;
    float acc2 = 0.f;
#pragma unroll
    for (int k = 0; k < LAT; k++) acc2 += __shfl(hv, k, 32) * Wl[k * LAT + f];
    tpNext[(long long)v * LAT + f] = f2bf(acc2 * dv);
}

// ---------------- layer-3 gather: only the G readout nodes ----------------

__global__ void gather_readout_kernel(const int* __restrict__ rowptr, const int* __restrict__ csr_src,
                                      const u16* __restrict__ tp, const float* __restrict__ dinv,
                                      const float* __restrict__ bcur, const int* __restrict__ idx,
                                      float* __restrict__ pooled, int colOff, int G) {
    int vi = blockIdx.x * 8 + (int)(threadIdx.x >> 5);
    int f = threadIdx.x & 31;
    if (vi >= G) return;
    int v = idx[vi];
    int start = rowptr[v];
    int end = rowptr[v + 1];
    float acc = bf2f(tp[(long long)v * LAT + f]);
    int e = start;
    for (; e + 32 <= end; e += 32) {
        int s = csr_src[e + f];
#pragma unroll
        for (int jj = 0; jj < 32; jj += 8) {
            int s0 = __shfl(s, jj + 0, 32), s1 = __shfl(s, jj + 1, 32);
            int s2 = __shfl(s, jj + 2, 32), s3 = __shfl(s, jj + 3, 32);
            int s4 = __shfl(s, jj + 4, 32), s5 = __shfl(s, jj + 5, 32);
            int s6 = __shfl(s, jj + 6, 32), s7 = __shfl(s, jj + 7, 32);
            float r0 = bf2f(tp[(long long)s0 * LAT + f]);
            float r1 = bf2f(tp[(long long)s1 * LAT + f]);
            float r2 = bf2f(tp[(long long)s2 * LAT + f]);
            float r3 = bf2f(tp[(long long)s3 * LAT + f]);
            float r4 = bf2f(tp[(long long)s4 * LAT + f]);
            float r5 = bf2f(tp[(long long)s5 * LAT + f]);
            float r6 = bf2f(tp[(long long)s6 * LAT + f]);
            float r7 = bf2f(tp[(long long)s7 * LAT + f]);
            acc += ((r0 + r1) + (r2 + r3)) + ((r4 + r5) + (r6 + r7));
        }
    }
    int rem = end - e;
    if (rem > 0) {
        int s = (f < rem) ? csr_src[e + f] : 0;
        for (int j = 0; j < rem; j++) {
            int sj = __shfl(s, j, 32);
            acc += bf2f(tp[(long long)sj * LAT + f]);
        }
    }
    float hv = tanhf(dinv[v] * acc + bcur[f]);
    pooled[(long long)vi * (3 * LAT) + colOff + f] = hv;
}

// ---------------- MLP head ----------------

__global__ void mlp_head_kernel(const float* __restrict__ pooled,
                                const float* __restrict__ Wl1, const float* __restrict__ bl1,
                                const float* __restrict__ Wl2, const float* __restrict__ bl2,
                                float* __restrict__ out, int G) {
    __shared__ float prow[3 * LAT];
    __shared__ float red0[HID];
    __shared__ float red1[HID];
    int g = blockIdx.x;
    int j = threadIdx.x;
    if (j < 3 * LAT) prow[j] = pooled[(long long)g * (3 * LAT) + j];
    __syncthreads();
    float acc = bl1[j];
#pragma unroll 8
    for (int k = 0; k < 3 * LAT; k++) acc += prow[k] * Wl1[k * HID + j];
    float hj = fmaxf(acc, 0.f);
    red0[j] = hj * Wl2[j * 2 + 0];
    red1[j] = hj * Wl2[j * 2 + 1];
    __syncthreads();
    for (int s = HID / 2; s > 0; s >>= 1) {
        if (j < s) { red0[j] += red0[j + s]; red1[j] += red1[j + s]; }
        __syncthreads();
    }
    if (j == 0) {
        float l0 = red0[0] + bl2[0];
        float l1 = red1[0] + bl2[1];
        float m = fmaxf(l0, l1);
        float lse = m + logf(expf(l0 - m) + expf(l1 - m));
        out[(long long)g * 2 + 0] = l0 - lse;
        out[(long long)g * 2 + 1] = l1 - lse;
    }
}

// ---------------- launch ----------------

extern "C" void kernel_launch(void* const* d_in, const int* in_sizes, int n_in,
                              void* d_out, int out_size, void* d_ws, size_t ws_size,
                              hipStream_t stream) {
    const float* x    = (const float*)d_in[0];
    const int*   ei   = (const int*)d_in[1];
    const int*   batch= (const int*)d_in[2];
    const float* W1   = (const float*)d_in[3];
    const float* b1   = (const float*)d_in[4];
    const float* W2   = (const float*)d_in[5];
    const float* b2   = (const float*)d_in[6];
    const float* W3   = (const float*)d_in[7];
    const float* b3   = (const float*)d_in[8];
    const float* Wl1  = (const float*)d_in[9];
    const float* bl1  = (const float*)d_in[10];
    const float* Wl2  = (const float*)d_in[11];
    const float* bl2  = (const float*)d_in[12];
    float* out = (float*)d_out;

    const int N = in_sizes[2];
    const long long E = (long long)in_sizes[1] / 2;
    const int G = out_size / 2;
    const int K = (N + RANGE - 1) >> RSHIFT;
    const int capT = G * LCAP;

    // workspace layout
    char* ws = (char*)d_ws;
    size_t off = 0;
    char*  regionA = ws + off;           off += (size_t)K * CAP * 4;  // padded pairs; later tpA (bf16 N*32)
    char*  bufB    = ws + off;           off += (size_t)N * LAT * 2;  // tpB (bf16)
    int*   csr_src = (int*)  (ws + off); off += (size_t)E * 4;
    float* dinv    = (float*)(ws + off); off += (size_t)N * 4;
    int*   rowptr  = (int*)  (ws + off); off += (size_t)(N + 1) * 4;
    int*   pmap    = (int*)  (ws + off); off += (size_t)N * 4;
    int*   idx     = (int*)  (ws + off); off += (size_t)G * 4;
    float* pooled  = (float*)(ws + off); off += (size_t)G * (3 * LAT) * 4;
    int*   bucketStart  = (int*)(ws + off); off += (KMAX + 1) * 4;
    int*   bucketCursor = (int*)(ws + off); off += KMAX * 4;
    int*   offs    = (int*)  (ws + off); off += (size_t)G * 4;
    int*   totalT  = (int*)  (ws + off); off += 4;
    int*   list    = (int*)  (ws + off); off += (size_t)capT * 4;

    unsigned int* pairs = (unsigned int*)regionA;   // dead before gemm_in writes tpA
    u16* tpA = (u16*)regionA;
    u16* tpB = (u16*)bufB;

    const int BS = 256;
    const int gatherBlocks = (N + 7) / 8;
    const int g2Blocks = (capT + 7) / 8;     // early-exit via totalT device count
    const int groBlocks = (G + 7) / 8;
    const int ginBlocks = (N + GIN_ROWS - 1) / GIN_ROWS;
    const int partBlocks = (int)((E + PART_CH - 1) / PART_CH);

    // ---- CSR build: padded-region radix partition (no pre-hist/pre-scan) ----
    pmap_kernel<<<(N + BS - 1) / BS, BS, 0, stream>>>(batch, pmap, N);
    compute_idx_kernel<<<(G + BS - 1) / BS, BS, 0, stream>>>(batch, idx, N, G);
    init_cursor_kernel<<<(K + BS - 1) / BS, BS, 0, stream>>>(bucketCursor, K);
    partition_kernel<<<partBlocks, PART_T, 0, stream>>>(ei, bucketCursor, pairs, E, K);
    post_scan_kernel<<<1, KMAX, 0, stream>>>(bucketCursor, bucketStart, K, (int)E, rowptr, N);
    build_csr_kernel<<<K, RANGE, 0, stream>>>(pairs, bucketStart, rowptr, dinv, csr_src, N);

    // ---- layer-2 worklist (readout nodes + in-neighbors) ----
    rscan_kernel<<<1, 256, 0, stream>>>(rowptr, idx, offs, totalT, G);
    rfill_kernel<<<(G + 3) / 4, BS, 0, stream>>>(rowptr, csr_src, idx, offs, list, G);

    // ---- layer 1 transform ----
    gemm_in_kernel<<<ginBlocks, BS, 0, stream>>>(x, W1, dinv, tpA, N);

    // ---- layer 1 over all N; layer 2 over worklist; layer 3 over readout ----
    gather_fused_kernel<<<gatherBlocks, BS, 0, stream>>>(rowptr, csr_src, tpA, dinv, b1, pmap,
                                                         pooled, 0, W2, tpB,
                                                         (const int*)nullptr, (const int*)nullptr, N);
    gather_fused_kernel<<<g2Blocks, BS, 0, stream>>>(rowptr, csr_src, tpB, dinv, b2, pmap,
                                                     pooled, LAT, W3, tpA,
                                                     list, totalT, capT);
    gather_readout_kernel<<<groBlocks, BS, 0, stream>>>(rowptr, csr_src, tpA, dinv, b3, idx,
                                                        pooled, 2 * LAT, G);

    // ---- MLP head ----
    mlp_head_kernel<<<G, HID, 0, stream>>>(pooled, Wl1, bl1, Wl2, bl2, out, G);
}